// Round 4
// baseline (3293.933 us; speedup 1.0000x reference)
//
#include <hip/hip_runtime.h>
#include <cfloat>
#include <cstdint>

#define NV    8192
#define NM    32768
#define KNN   16
#define CIN   32
#define COUT  64
#define CPROV 96
#define WAVES 16     // waves per knn block = N-chunks
#define WCH   512    // NV / WAVES candidates per wave
#define CAPB  8      // FIFO depth per lane
#define MT    8      // grid points per wave in mlp kernel
#define MLP_BLOCK 1024
#define WPB   (MLP_BLOCK/64)

// ===========================================================================
// KNN v2: same validated d2/key/gate semantics as before (golden d2 path,
// u64 (d2,idx) keys, tau-seeded gate, branchless sorted insert, LDS FIFO),
// restructured for occupancy:
//   - 1 block = 16 waves over the SAME 64 grid points; wave w scans chunk w
//     (512 verts) -> 8192 waves total = 32 waves/CU (was 2048 = 8/CU).
//   - candidates read as wave-uniform loads from pre-packed float4
//     (r0,r1,r2,rr): no LDS staging, no barriers in the scan loop.
//   - per-wave sorted top-16 lists merged in-block via a 4-round bitonic
//     merge tree in LDS; knn_idx written directly (no cand buffer, no
//     merge kernel, -19.6 MB of HBM writes).
// min-16-of-union is associative over any partition of N, so the result is
// bit-identical to the previous NCH=4 partial+merge pipeline.
// ===========================================================================

__device__ __forceinline__ unsigned long long d2key(float d2, unsigned int idx) {
    unsigned int b = __float_as_uint(d2);
    b ^= (b & 0x80000000u) ? 0xFFFFFFFFu : 0x80000000u;  // total-order map
    return ((unsigned long long)b << 32) | idx;
}

__device__ __forceinline__ float key_d2f(unsigned long long key) {
    unsigned int b = (unsigned int)(key >> 32);
    b = (b & 0x80000000u) ? (b ^ 0x80000000u) : ~b;      // inverse map
    return __uint_as_float(b);
}

__device__ __forceinline__ void key_insert(unsigned long long* a,
                                           unsigned long long key) {
    // branchless sorted (ascending) insert-and-drop-max
#pragma unroll
    for (int i = KNN - 1; i >= 1; --i) {
        unsigned long long hi = (a[i-1] > key) ? a[i-1] : key;
        a[i] = (hi < a[i]) ? hi : a[i];
    }
    a[0] = (key < a[0]) ? key : a[0];
}

__device__ __forceinline__ int bin_of(float x) {
    int b = (int)(x * 32.0f);
    return min(31, max(0, b));
}

__global__ __launch_bounds__(256) void bin_count_kernel(
    const float* __restrict__ verts, int* __restrict__ counts)
{
    int v = blockIdx.x * 256 + threadIdx.x;
    int bx = bin_of(verts[v * 3 + 0]);
    int by = bin_of(verts[v * 3 + 1]);
    int bz = bin_of(verts[v * 3 + 2]);
    atomicAdd(&counts[(bx * 32 + by) * 32 + bz], 1);
}

__global__ __launch_bounds__(1024) void prefix_kernel(
    const int* __restrict__ counts, int* __restrict__ prefix)
{
    __shared__ int lds[1024];
    int tid = threadIdx.x;
    int local[32]; int s = 0;
#pragma unroll
    for (int i = 0; i < 32; ++i) { local[i] = counts[tid * 32 + i]; s += local[i]; }
    lds[tid] = s; __syncthreads();
    for (int off = 1; off < 1024; off <<= 1) {
        int v = (tid >= off) ? lds[tid - off] : 0;
        __syncthreads();
        lds[tid] += v;
        __syncthreads();
    }
    int run = lds[tid] - s;
#pragma unroll
    for (int i = 0; i < 32; ++i) { prefix[tid * 32 + i] = run; run += local[i]; }
    if (tid == 1023) prefix[32768] = run;
}

// tau[m] = 3*(R+1)^2 where radius-R cell cube holds >= 16 points (validated R6/R8)
__global__ __launch_bounds__(256) void radius_kernel(
    const float* __restrict__ grid_verts, const int* __restrict__ prefix,
    float* __restrict__ tau)
{
    int m = blockIdx.x * 256 + threadIdx.x;
    int bx = bin_of(grid_verts[m * 3 + 0]);
    int by = bin_of(grid_verts[m * 3 + 1]);
    int bz = bin_of(grid_verts[m * 3 + 2]);
    int R = 1;
    for (; R < 32; ++R) {
        int cnt = 0;
        int xlo = max(0, bx - R), xhi = min(31, bx + R);
        int ylo = max(0, by - R), yhi = min(31, by + R);
        int zlo = max(0, bz - R), zhi = min(31, bz + R);
        for (int x = xlo; x <= xhi; ++x)
            for (int y = ylo; y <= yhi; ++y) {
                int c = (x * 32 + y) * 32;
                cnt += prefix[c + zhi + 1] - prefix[c + zlo];
            }
        if (cnt >= KNN) break;
    }
    float Rp = (float)(R + 1);
    tau[m] = 3.0f * Rp * Rp;
}

// pack (r0,r1,r2,rr) with the EXACT rounding sequence of the old LDS staging
__global__ __launch_bounds__(256) void pack_kernel(
    const float* __restrict__ verts, float4* __restrict__ vp)
{
    int v = blockIdx.x * 256 + threadIdx.x;
    float r0 = __fmul_rn(verts[v * 3 + 0], 32.0f);
    float r1 = __fmul_rn(verts[v * 3 + 1], 32.0f);
    float r2 = __fmul_rn(verts[v * 3 + 2], 32.0f);
    float rr = __fadd_rn(__fadd_rn(__fmul_rn(r0, r0), __fmul_rn(r1, r1)),
                         __fmul_rn(r2, r2));
    vp[v] = make_float4(r0, r1, r2, rr);
}

#define CSWAP(i, j) { unsigned long long x_ = a[i], y_ = a[j]; \
                      bool c_ = x_ < y_; \
                      a[i] = c_ ? x_ : y_; a[j] = c_ ? y_ : x_; }

__global__ __launch_bounds__(1024, 8) void knn_block_kernel(
    const float4* __restrict__ vp,
    const float* __restrict__ grid_verts,
    const float* __restrict__ tau,
    int* __restrict__ knn_idx)
{
    __shared__ unsigned long long buf[8192];   // 64 KB: scan FIFO, then merge slots
    const int tid  = threadIdx.x;
    const int lane = tid & 63;
    const int w    = tid >> 6;                 // wave id == chunk id
    const int m    = blockIdx.x * 64 + lane;

    const float q0 = __fmul_rn(grid_verts[m * 3 + 0], 32.0f);
    const float q1 = __fmul_rn(grid_verts[m * 3 + 1], 32.0f);
    const float q2 = __fmul_rn(grid_verts[m * 3 + 2], 32.0f);
    const float qq = __fadd_rn(__fadd_rn(__fmul_rn(q0, q0), __fmul_rn(q1, q1)),
                               __fmul_rn(q2, q2));

    // seed = key(bound), idx 0; bound > all golden top-16 d2 (validated margin)
    const float bound = tau[m] + 0.13f;
    unsigned int bb = __float_as_uint(bound) ^ 0x80000000u;  // bound > 0
    const unsigned long long seed = ((unsigned long long)bb << 32);

    unsigned long long a[KNN];
#pragma unroll
    for (int s = 0; s < KNN; ++s) a[s] = seed;
    float gd = bound;      // d2-domain gate = d2 part of a[15]
    int cnt = 0;

    // wave-uniform candidate base -> scalar/broadcast loads, no staging
    const int base = __builtin_amdgcn_readfirstlane(w << 9);  // w * WCH
    const float4* __restrict__ vw = vp + base;

    for (int rnd = 0; rnd < 4; ++rnd) {
        const int t0 = rnd * (WCH / 4);
        for (int t = t0; t < t0 + (WCH / 4); t += 8) {
            float d2v[8];
#pragma unroll
            for (int k = 0; k < 8; ++k) {
                float4 v = vw[t + k];
                float dot = fmaf(q2, v.z, fmaf(q1, v.y, __fmul_rn(q0, v.x)));
                // == (qq+rr) - 2*dot bit-exactly (2*dot exact)
                d2v[k] = fmaf(-2.0f, dot, __fadd_rn(qq, v.w));
            }
#pragma unroll
            for (int k = 0; k < 8; ++k) {
                if (d2v[k] <= gd) {     // conservative: ties resolved by insert
                    unsigned long long key = d2key(d2v[k], base + t + k);
                    if (cnt < CAPB) { buf[cnt * 1024 + tid] = key; ++cnt; }
                    else {  // rare overflow: exact direct insert, tighten gate
                        key_insert(a, key);
                        gd = key_d2f(a[KNN - 1]);
                    }
                }
            }
        }
        // drain private FIFO (lane-private columns; no barrier needed)
        int mx = cnt;
#pragma unroll
        for (int off = 32; off; off >>= 1) mx = max(mx, __shfl_xor(mx, off));
        for (int k = 0; k < mx; ++k) {
            unsigned long long key = (k < cnt) ? buf[k * 1024 + tid] : ~0ULL;
            key_insert(a, key);
        }
        if (mx) gd = key_d2f(a[KNN - 1]);
        cnt = 0;
    }

    // ---- cross-wave merge tree: 16 sorted lists -> 1, bitonic in registers ----
    // round half: waves [half,2*half) publish, waves [0,half) merge slot w.
    for (int half = 8; half >= 1; half >>= 1) {
        __syncthreads();                       // prior reads done before overwrite
        if (w >= half && w < 2 * half) {
            unsigned long long* dst = &buf[(w - half) * 1024];
#pragma unroll
            for (int s = 0; s < KNN; ++s) dst[s * 64 + lane] = a[s];
        }
        __syncthreads();
        if (w < half) {
            const unsigned long long* src = &buf[w * 1024];
            // L[i] = min(a[i], b[15-i]) : 16 smallest of union, bitonic
#pragma unroll
            for (int i = 0; i < KNN; ++i) {
                unsigned long long b = src[(KNN - 1 - i) * 64 + lane];
                a[i] = (b < a[i]) ? b : a[i];
            }
            // clean bitonic-16 -> ascending (static indices, no scratch)
            CSWAP(0, 8)  CSWAP(1, 9)  CSWAP(2, 10) CSWAP(3, 11)
            CSWAP(4, 12) CSWAP(5, 13) CSWAP(6, 14) CSWAP(7, 15)
            CSWAP(0, 4)  CSWAP(1, 5)  CSWAP(2, 6)  CSWAP(3, 7)
            CSWAP(8, 12) CSWAP(9, 13) CSWAP(10, 14) CSWAP(11, 15)
            CSWAP(0, 2)  CSWAP(1, 3)  CSWAP(4, 6)  CSWAP(5, 7)
            CSWAP(8, 10) CSWAP(9, 11) CSWAP(12, 14) CSWAP(13, 15)
            CSWAP(0, 1)  CSWAP(2, 3)  CSWAP(4, 5)  CSWAP(6, 7)
            CSWAP(8, 9)  CSWAP(10, 11) CSWAP(12, 13) CSWAP(14, 15)
        }
    }

    if (w == 0) {
#pragma unroll
        for (int s = 0; s < KNN; ++s)
            knn_idx[m * KNN + s] = (int)(a[s] & 0xFFFFFFFFu);
    }
}

// ===========================================================================
// MLP precompute (unchanged — passed)
// ===========================================================================

__global__ void const_kernel(const float* __restrict__ ew1, float* __restrict__ cst)
{
    int c = threadIdx.x;   // 64 threads
    float w0 = ew1[32 * 64 + c], w1 = ew1[33 * 64 + c], w2 = ew1[34 * 64 + c];
    float v[9] = { w0, w1, w2, w0*w0, w1*w1, w2*w2, w0*w1, w0*w2, w1*w2 };
#pragma unroll
    for (int k = 0; k < 9; ++k) {
#pragma unroll
        for (int off = 32; off; off >>= 1) v[k] += __shfl_xor(v[k], off);
    }
    if (c == 0) {
        cst[0] = v[0]; cst[1] = v[1]; cst[2] = v[2];
        cst[3] = v[3]; cst[4] = v[4]; cst[5] = v[5];
        cst[6] = v[6]; cst[7] = v[7]; cst[8] = v[8];
    }
}

__global__ __launch_bounds__(256) void pre_edge_kernel(
    const float* __restrict__ feats, const float* __restrict__ ew1,
    const float* __restrict__ eb1, float* __restrict__ pre,
    float* __restrict__ aux)
{
    int t = blockIdx.x * 256 + threadIdx.x;
    int n = t >> 6, c = t & 63;
    float acc = eb1[c];
#pragma unroll
    for (int i = 0; i < CIN; ++i)
        acc = fmaf(feats[n * CIN + i], ew1[i * COUT + c], acc);
    pre[t] = acc;

    float w0 = ew1[32 * 64 + c], w1 = ew1[33 * 64 + c], w2 = ew1[34 * 64 + c];
    float v[5] = { acc, acc * acc, acc * w0, acc * w1, acc * w2 };
#pragma unroll
    for (int k = 0; k < 5; ++k) {
#pragma unroll
        for (int off = 32; off; off >>= 1) v[k] += __shfl_xor(v[k], off);
    }
    if (c == 0) {
        aux[n * 8 + 0] = v[0]; aux[n * 8 + 1] = v[1];
        aux[n * 8 + 2] = v[2]; aux[n * 8 + 3] = v[3]; aux[n * 8 + 4] = v[4];
    }
}

// ===========================================================================
// Main MLP (unchanged — passed)
// ===========================================================================
__device__ __forceinline__ float gelu_fast(float x) {
    float t = fmaf(0.044715f, x * x, 1.0f);
    float u = 0.7978845608028654f * x * t;
    float e = __expf(-2.0f * u);
    return x * __builtin_amdgcn_rcpf(1.0f + e);
}

__device__ __forceinline__ float lane_bcast(float v, int lane) {
    return __uint_as_float(__builtin_amdgcn_readlane(__float_as_uint(v), lane));
}

__global__ __launch_bounds__(MLP_BLOCK) void mlp_kernel(
    const float* __restrict__ verts,
    const float* __restrict__ grid_verts,
    const float* __restrict__ grid_feat,
    const float* __restrict__ pre,
    const float* __restrict__ aux,
    const float* __restrict__ cst,
    const int*   __restrict__ knn_idx,
    const float* __restrict__ ew1,
    const float* __restrict__ eg1, const float* __restrict__ ebt1,
    const float* __restrict__ ew2, const float* __restrict__ eb2,
    const float* __restrict__ ow1, const float* __restrict__ ob1,
    const float* __restrict__ og1, const float* __restrict__ obt1,
    const float* __restrict__ ow2, const float* __restrict__ ob2,
    float* __restrict__ out)
{
    __shared__ float s_ew1r[3 * 64];
    __shared__ float s_ew2[64 * 64];
    __shared__ float s_ow1[160 * 64];
    __shared__ float s_ow2[64 * 64];
    __shared__ float s_eg1[64], s_ebt1[64], s_eb2[64];
    __shared__ float s_ob1[64], s_og1[64], s_obt1[64], s_ob2[64];

    const int tid = threadIdx.x;
    for (int t = tid; t < 3 * 64;  t += MLP_BLOCK) s_ew1r[t] = ew1[32 * 64 + t];
    for (int t = tid; t < 64 * 64; t += MLP_BLOCK) s_ew2[t]  = ew2[t];
    for (int t = tid; t < 160 * 64; t += MLP_BLOCK) s_ow1[t] = ow1[t];
    for (int t = tid; t < 64 * 64; t += MLP_BLOCK) s_ow2[t]  = ow2[t];
    if (tid < 64) {
        s_eg1[tid] = eg1[tid];  s_ebt1[tid] = ebt1[tid]; s_eb2[tid] = eb2[tid];
        s_ob1[tid] = ob1[tid];  s_og1[tid] = og1[tid];
        s_obt1[tid] = obt1[tid]; s_ob2[tid] = ob2[tid];
    }
    __syncthreads();

    const int lane = tid & 63;
    const int wave = tid >> 6;
    const int c    = lane;
    const int grp  = blockIdx.x * WPB + wave;
    const int m0   = __builtin_amdgcn_readfirstlane(grp * MT);

    const float Ws0 = cst[0], Ws1 = cst[1], Ws2 = cst[2];
    const float Gxx = cst[3], Gyy = cst[4], Gzz = cst[5];
    const float Gxy = cst[6], Gxz = cst[7], Gyz = cst[8];

    float gvx[MT], gvy[MT], gvz[MT];
#pragma unroll
    for (int p = 0; p < MT; ++p) {
        gvx[p] = grid_verts[(m0 + p) * 3 + 0];
        gvy[p] = grid_verts[(m0 + p) * 3 + 1];
        gvz[p] = grid_verts[(m0 + p) * 3 + 2];
    }

    float gsum[MT];
#pragma unroll
    for (int p = 0; p < MT; ++p) gsum[p] = 0.0f;

    const float inv64 = 1.0f / 64.0f;
    for (int p = 0; p < MT; ++p) {
        for (int j = 0; j < KNN; ++j) {
            int n = __builtin_amdgcn_readfirstlane(knn_idx[(m0 + p) * KNN + j]);
            float S1  = aux[n * 8 + 0], Q = aux[n * 8 + 1];
            float P1x = aux[n * 8 + 2], P1y = aux[n * 8 + 3], P1z = aux[n * 8 + 4];
            float rx = verts[n * 3 + 0] - gvx[p];
            float ry = verts[n * 3 + 1] - gvy[p];
            float rz = verts[n * 3 + 2] - gvz[p];
            float hv = pre[(size_t)n * COUT + c];
            hv = fmaf(rx, s_ew1r[0 * 64 + c], hv);
            hv = fmaf(ry, s_ew1r[1 * 64 + c], hv);
            hv = fmaf(rz, s_ew1r[2 * 64 + c], hv);
            float s1 = S1 + rx * Ws0 + ry * Ws1 + rz * Ws2;
            float s2 = Q + 2.0f * (rx * P1x + ry * P1y + rz * P1z)
                     + rx * rx * Gxx + ry * ry * Gyy + rz * rz * Gzz
                     + 2.0f * (rx * ry * Gxy + rx * rz * Gxz + ry * rz * Gyz);
            float mean = s1 * inv64;
            float var  = s2 * inv64 - mean * mean;
            float xn = (hv - mean) * rsqrtf(var + 1e-5f);
            gsum[p] += gelu_fast(xn * s_eg1[c] + s_ebt1[c]);
        }
    }

    float A[MT];
#pragma unroll
    for (int p = 0; p < MT; ++p) { gsum[p] *= (1.0f / 16.0f); A[p] = s_eb2[c]; }
    for (int jj = 0; jj < 64; ++jj) {
        float w = s_ew2[jj * 64 + c];
#pragma unroll
        for (int p = 0; p < MT; ++p)
            A[p] = fmaf(lane_bcast(gsum[p], jj), w, A[p]);
    }

    float gfa[MT], gfb[MT];
#pragma unroll
    for (int p = 0; p < MT; ++p) {
        gfa[p] = grid_feat[(size_t)(m0 + p) * CPROV + c];
        gfb[p] = grid_feat[(size_t)(m0 + p) * CPROV + 64 + (c & 31)];
    }
    float t1[MT];
#pragma unroll
    for (int p = 0; p < MT; ++p) t1[p] = s_ob1[c];
    for (int jj = 0; jj < 64; ++jj) {
        float w = s_ow1[jj * 64 + c];
#pragma unroll
        for (int p = 0; p < MT; ++p)
            t1[p] = fmaf(lane_bcast(A[p], jj), w, t1[p]);
    }
    for (int i = 0; i < 64; ++i) {
        float w = s_ow1[(64 + i) * 64 + c];
#pragma unroll
        for (int p = 0; p < MT; ++p)
            t1[p] = fmaf(lane_bcast(gfa[p], i), w, t1[p]);
    }
    for (int i = 0; i < 32; ++i) {
        float w = s_ow1[(128 + i) * 64 + c];
#pragma unroll
        for (int p = 0; p < MT; ++p)
            t1[p] = fmaf(lane_bcast(gfb[p], i), w, t1[p]);
    }

#pragma unroll
    for (int p = 0; p < MT; ++p) {
        float x = t1[p];
        float s = x, s2 = x * x;
#pragma unroll
        for (int off = 32; off; off >>= 1) {
            s  += __shfl_xor(s, off);
            s2 += __shfl_xor(s2, off);
        }
        float mean = s * inv64;
        float var  = s2 * inv64 - mean * mean;
        float xn = (x - mean) * rsqrtf(var + 1e-5f);
        t1[p] = gelu_fast(xn * s_og1[c] + s_obt1[c]);
    }

    float o[MT];
#pragma unroll
    for (int p = 0; p < MT; ++p) o[p] = s_ob2[c];
    for (int jj = 0; jj < 64; ++jj) {
        float w = s_ow2[jj * 64 + c];
#pragma unroll
        for (int p = 0; p < MT; ++p)
            o[p] = fmaf(lane_bcast(t1[p], jj), w, o[p]);
    }
#pragma unroll
    for (int p = 0; p < MT; ++p)
        out[(size_t)(m0 + p) * COUT + c] = o[p];
}

// ---------------------------------------------------------------------------
extern "C" void kernel_launch(void* const* d_in, const int* in_sizes, int n_in,
                              void* d_out, int out_size, void* d_ws, size_t ws_size,
                              hipStream_t stream)
{
    const float* verts  = (const float*)d_in[0];
    const float* feats  = (const float*)d_in[1];
    const float* gverts = (const float*)d_in[2];
    const float* gfeat  = (const float*)d_in[3];
    const float* ew1    = (const float*)d_in[4];
    const float* eb1    = (const float*)d_in[5];
    const float* eg1    = (const float*)d_in[6];
    const float* ebt1   = (const float*)d_in[7];
    const float* ew2    = (const float*)d_in[8];
    const float* eb2    = (const float*)d_in[9];
    const float* ow1    = (const float*)d_in[10];
    const float* ob1    = (const float*)d_in[11];
    const float* og1    = (const float*)d_in[12];
    const float* obt1   = (const float*)d_in[13];
    const float* ow2    = (const float*)d_in[14];
    const float* ob2    = (const float*)d_in[15];
    float* out = (float*)d_out;

    char* ws = (char*)d_ws;
    int*    counts  = (int*)(ws + 0);              // 128 KB
    int*    prefix  = (int*)(ws + 131072);         // 32769 ints
    float*  tau     = (float*)(ws + 262152);       // 128 KB
    int*    knn_idx = (int*)(ws + 393224);         // 2 MB -> ends 2490376
    float*  pre     = (float*)(ws + 2490376);      // 2 MB
    float*  aux     = (float*)(ws + 4587528);      // 256 KB
    float*  cst     = (float*)(ws + 4849672);      // 64 B
    float4* vp      = (float4*)(ws + 4849744);     // 128 KB packed verts

    hipMemsetAsync(counts, 0, 32768 * sizeof(int), stream);
    bin_count_kernel<<<NV / 256, 256, 0, stream>>>(verts, counts);
    prefix_kernel<<<1, 1024, 0, stream>>>(counts, prefix);
    radius_kernel<<<NM / 256, 256, 0, stream>>>(gverts, prefix, tau);
    pack_kernel<<<NV / 256, 256, 0, stream>>>(verts, vp);
    knn_block_kernel<<<NM / 64, 1024, 0, stream>>>(vp, gverts, tau, knn_idx);
    pre_edge_kernel<<<(NV * COUT) / 256, 256, 0, stream>>>(feats, ew1, eb1, pre, aux);
    const_kernel<<<1, 64, 0, stream>>>(ew1, cst);
    mlp_kernel<<<NM / (MT * WPB), MLP_BLOCK, 0, stream>>>(verts, gverts, gfeat,
        pre, aux, cst, knn_idx,
        ew1, eg1, ebt1, ew2, eb2, ow1, ob1, og1, obt1, ow2, ob2, out);
}

// Round 5
// 343.833 us; speedup vs baseline: 9.5800x; 9.5800x over previous
//
#include <hip/hip_runtime.h>
#include <cfloat>
#include <cstdint>

#define NV    8192
#define NM    32768
#define KNN   16
#define CIN   32
#define COUT  64
#define CPROV 96
#define WAVES 16     // waves per knn block = N-chunks
#define WCH   512    // NV / WAVES candidates per wave
#define CAPB  8      // FIFO depth per lane
#define MT    8      // grid points per wave in mlp kernel
#define MLP_BLOCK 1024
#define WPB   (MLP_BLOCK/64)

// ===========================================================================
// KNN v2.1: identical algorithm to v2 (R4 run: PASSED, absmax unchanged).
// R4 post-mortem: __launch_bounds__(1024,8) capped VGPR at 64; the a[16]
// u64 heap (32 VGPR) + scan state forced a full spill to scratch ->
// 11.6 GB of scratch traffic, VALUBusy 3.4%, 3080 us. Fix: (1024,4) ->
// VGPR cap 128, heap stays in registers, 1 block/CU (16 waves/CU, still
// 2.5x the old kernel's 6.4 waves/CU).
// ===========================================================================

__device__ __forceinline__ unsigned long long d2key(float d2, unsigned int idx) {
    unsigned int b = __float_as_uint(d2);
    b ^= (b & 0x80000000u) ? 0xFFFFFFFFu : 0x80000000u;  // total-order map
    return ((unsigned long long)b << 32) | idx;
}

__device__ __forceinline__ float key_d2f(unsigned long long key) {
    unsigned int b = (unsigned int)(key >> 32);
    b = (b & 0x80000000u) ? (b ^ 0x80000000u) : ~b;      // inverse map
    return __uint_as_float(b);
}

__device__ __forceinline__ void key_insert(unsigned long long* a,
                                           unsigned long long key) {
    // branchless sorted (ascending) insert-and-drop-max
#pragma unroll
    for (int i = KNN - 1; i >= 1; --i) {
        unsigned long long hi = (a[i-1] > key) ? a[i-1] : key;
        a[i] = (hi < a[i]) ? hi : a[i];
    }
    a[0] = (key < a[0]) ? key : a[0];
}

__device__ __forceinline__ int bin_of(float x) {
    int b = (int)(x * 32.0f);
    return min(31, max(0, b));
}

__global__ __launch_bounds__(256) void bin_count_kernel(
    const float* __restrict__ verts, int* __restrict__ counts)
{
    int v = blockIdx.x * 256 + threadIdx.x;
    int bx = bin_of(verts[v * 3 + 0]);
    int by = bin_of(verts[v * 3 + 1]);
    int bz = bin_of(verts[v * 3 + 2]);
    atomicAdd(&counts[(bx * 32 + by) * 32 + bz], 1);
}

__global__ __launch_bounds__(1024) void prefix_kernel(
    const int* __restrict__ counts, int* __restrict__ prefix)
{
    __shared__ int lds[1024];
    int tid = threadIdx.x;
    int local[32]; int s = 0;
#pragma unroll
    for (int i = 0; i < 32; ++i) { local[i] = counts[tid * 32 + i]; s += local[i]; }
    lds[tid] = s; __syncthreads();
    for (int off = 1; off < 1024; off <<= 1) {
        int v = (tid >= off) ? lds[tid - off] : 0;
        __syncthreads();
        lds[tid] += v;
        __syncthreads();
    }
    int run = lds[tid] - s;
#pragma unroll
    for (int i = 0; i < 32; ++i) { prefix[tid * 32 + i] = run; run += local[i]; }
    if (tid == 1023) prefix[32768] = run;
}

// tau[m] = 3*(R+1)^2 where radius-R cell cube holds >= 16 points (validated R6/R8)
__global__ __launch_bounds__(256) void radius_kernel(
    const float* __restrict__ grid_verts, const int* __restrict__ prefix,
    float* __restrict__ tau)
{
    int m = blockIdx.x * 256 + threadIdx.x;
    int bx = bin_of(grid_verts[m * 3 + 0]);
    int by = bin_of(grid_verts[m * 3 + 1]);
    int bz = bin_of(grid_verts[m * 3 + 2]);
    int R = 1;
    for (; R < 32; ++R) {
        int cnt = 0;
        int xlo = max(0, bx - R), xhi = min(31, bx + R);
        int ylo = max(0, by - R), yhi = min(31, by + R);
        int zlo = max(0, bz - R), zhi = min(31, bz + R);
        for (int x = xlo; x <= xhi; ++x)
            for (int y = ylo; y <= yhi; ++y) {
                int c = (x * 32 + y) * 32;
                cnt += prefix[c + zhi + 1] - prefix[c + zlo];
            }
        if (cnt >= KNN) break;
    }
    float Rp = (float)(R + 1);
    tau[m] = 3.0f * Rp * Rp;
}

// pack (r0,r1,r2,rr) with the EXACT rounding sequence of the old LDS staging
__global__ __launch_bounds__(256) void pack_kernel(
    const float* __restrict__ verts, float4* __restrict__ vp)
{
    int v = blockIdx.x * 256 + threadIdx.x;
    float r0 = __fmul_rn(verts[v * 3 + 0], 32.0f);
    float r1 = __fmul_rn(verts[v * 3 + 1], 32.0f);
    float r2 = __fmul_rn(verts[v * 3 + 2], 32.0f);
    float rr = __fadd_rn(__fadd_rn(__fmul_rn(r0, r0), __fmul_rn(r1, r1)),
                         __fmul_rn(r2, r2));
    vp[v] = make_float4(r0, r1, r2, rr);
}

#define CSWAP(i, j) { unsigned long long x_ = a[i], y_ = a[j]; \
                      bool c_ = x_ < y_; \
                      a[i] = c_ ? x_ : y_; a[j] = c_ ? y_ : x_; }

__global__ __launch_bounds__(1024, 4) void knn_block_kernel(
    const float4* __restrict__ vp,
    const float* __restrict__ grid_verts,
    const float* __restrict__ tau,
    int* __restrict__ knn_idx)
{
    __shared__ unsigned long long buf[8192];   // 64 KB: scan FIFO, then merge slots
    const int tid  = threadIdx.x;
    const int lane = tid & 63;
    const int w    = tid >> 6;                 // wave id == chunk id
    const int m    = blockIdx.x * 64 + lane;

    const float q0 = __fmul_rn(grid_verts[m * 3 + 0], 32.0f);
    const float q1 = __fmul_rn(grid_verts[m * 3 + 1], 32.0f);
    const float q2 = __fmul_rn(grid_verts[m * 3 + 2], 32.0f);
    const float qq = __fadd_rn(__fadd_rn(__fmul_rn(q0, q0), __fmul_rn(q1, q1)),
                               __fmul_rn(q2, q2));

    // seed = key(bound), idx 0; bound > all golden top-16 d2 (validated margin)
    const float bound = tau[m] + 0.13f;
    unsigned int bb = __float_as_uint(bound) ^ 0x80000000u;  // bound > 0
    const unsigned long long seed = ((unsigned long long)bb << 32);

    unsigned long long a[KNN];
#pragma unroll
    for (int s = 0; s < KNN; ++s) a[s] = seed;
    float gd = bound;      // d2-domain gate = d2 part of a[15]
    int cnt = 0;

    // wave-uniform candidate base -> scalar/broadcast loads, no staging
    const int base = __builtin_amdgcn_readfirstlane(w << 9);  // w * WCH
    const float4* __restrict__ vw = vp + base;

    for (int rnd = 0; rnd < 4; ++rnd) {
        const int t0 = rnd * (WCH / 4);
        for (int t = t0; t < t0 + (WCH / 4); t += 8) {
            float d2v[8];
#pragma unroll
            for (int k = 0; k < 8; ++k) {
                float4 v = vw[t + k];
                float dot = fmaf(q2, v.z, fmaf(q1, v.y, __fmul_rn(q0, v.x)));
                // == (qq+rr) - 2*dot bit-exactly (2*dot exact)
                d2v[k] = fmaf(-2.0f, dot, __fadd_rn(qq, v.w));
            }
#pragma unroll
            for (int k = 0; k < 8; ++k) {
                if (d2v[k] <= gd) {     // conservative: ties resolved by insert
                    unsigned long long key = d2key(d2v[k], base + t + k);
                    if (cnt < CAPB) { buf[cnt * 1024 + tid] = key; ++cnt; }
                    else {  // rare overflow: exact direct insert, tighten gate
                        key_insert(a, key);
                        gd = key_d2f(a[KNN - 1]);
                    }
                }
            }
        }
        // drain private FIFO (lane-private columns; no barrier needed)
        int mx = cnt;
#pragma unroll
        for (int off = 32; off; off >>= 1) mx = max(mx, __shfl_xor(mx, off));
        for (int k = 0; k < mx; ++k) {
            unsigned long long key = (k < cnt) ? buf[k * 1024 + tid] : ~0ULL;
            key_insert(a, key);
        }
        if (mx) gd = key_d2f(a[KNN - 1]);
        cnt = 0;
    }

    // ---- cross-wave merge tree: 16 sorted lists -> 1, bitonic in registers ----
    // round half: waves [half,2*half) publish, waves [0,half) merge slot w.
    for (int half = 8; half >= 1; half >>= 1) {
        __syncthreads();                       // prior reads done before overwrite
        if (w >= half && w < 2 * half) {
            unsigned long long* dst = &buf[(w - half) * 1024];
#pragma unroll
            for (int s = 0; s < KNN; ++s) dst[s * 64 + lane] = a[s];
        }
        __syncthreads();
        if (w < half) {
            const unsigned long long* src = &buf[w * 1024];
            // L[i] = min(a[i], b[15-i]) : 16 smallest of union, bitonic
#pragma unroll
            for (int i = 0; i < KNN; ++i) {
                unsigned long long b = src[(KNN - 1 - i) * 64 + lane];
                a[i] = (b < a[i]) ? b : a[i];
            }
            // clean bitonic-16 -> ascending (static indices, no scratch)
            CSWAP(0, 8)  CSWAP(1, 9)  CSWAP(2, 10) CSWAP(3, 11)
            CSWAP(4, 12) CSWAP(5, 13) CSWAP(6, 14) CSWAP(7, 15)
            CSWAP(0, 4)  CSWAP(1, 5)  CSWAP(2, 6)  CSWAP(3, 7)
            CSWAP(8, 12) CSWAP(9, 13) CSWAP(10, 14) CSWAP(11, 15)
            CSWAP(0, 2)  CSWAP(1, 3)  CSWAP(4, 6)  CSWAP(5, 7)
            CSWAP(8, 10) CSWAP(9, 11) CSWAP(12, 14) CSWAP(13, 15)
            CSWAP(0, 1)  CSWAP(2, 3)  CSWAP(4, 5)  CSWAP(6, 7)
            CSWAP(8, 9)  CSWAP(10, 11) CSWAP(12, 13) CSWAP(14, 15)
        }
    }

    if (w == 0) {
#pragma unroll
        for (int s = 0; s < KNN; ++s)
            knn_idx[m * KNN + s] = (int)(a[s] & 0xFFFFFFFFu);
    }
}

// ===========================================================================
// MLP precompute (unchanged — passed)
// ===========================================================================

__global__ void const_kernel(const float* __restrict__ ew1, float* __restrict__ cst)
{
    int c = threadIdx.x;   // 64 threads
    float w0 = ew1[32 * 64 + c], w1 = ew1[33 * 64 + c], w2 = ew1[34 * 64 + c];
    float v[9] = { w0, w1, w2, w0*w0, w1*w1, w2*w2, w0*w1, w0*w2, w1*w2 };
#pragma unroll
    for (int k = 0; k < 9; ++k) {
#pragma unroll
        for (int off = 32; off; off >>= 1) v[k] += __shfl_xor(v[k], off);
    }
    if (c == 0) {
        cst[0] = v[0]; cst[1] = v[1]; cst[2] = v[2];
        cst[3] = v[3]; cst[4] = v[4]; cst[5] = v[5];
        cst[6] = v[6]; cst[7] = v[7]; cst[8] = v[8];
    }
}

__global__ __launch_bounds__(256) void pre_edge_kernel(
    const float* __restrict__ feats, const float* __restrict__ ew1,
    const float* __restrict__ eb1, float* __restrict__ pre,
    float* __restrict__ aux)
{
    int t = blockIdx.x * 256 + threadIdx.x;
    int n = t >> 6, c = t & 63;
    float acc = eb1[c];
#pragma unroll
    for (int i = 0; i < CIN; ++i)
        acc = fmaf(feats[n * CIN + i], ew1[i * COUT + c], acc);
    pre[t] = acc;

    float w0 = ew1[32 * 64 + c], w1 = ew1[33 * 64 + c], w2 = ew1[34 * 64 + c];
    float v[5] = { acc, acc * acc, acc * w0, acc * w1, acc * w2 };
#pragma unroll
    for (int k = 0; k < 5; ++k) {
#pragma unroll
        for (int off = 32; off; off >>= 1) v[k] += __shfl_xor(v[k], off);
    }
    if (c == 0) {
        aux[n * 8 + 0] = v[0]; aux[n * 8 + 1] = v[1];
        aux[n * 8 + 2] = v[2]; aux[n * 8 + 3] = v[3]; aux[n * 8 + 4] = v[4];
    }
}

// ===========================================================================
// Main MLP (unchanged — passed)
// ===========================================================================
__device__ __forceinline__ float gelu_fast(float x) {
    float t = fmaf(0.044715f, x * x, 1.0f);
    float u = 0.7978845608028654f * x * t;
    float e = __expf(-2.0f * u);
    return x * __builtin_amdgcn_rcpf(1.0f + e);
}

__device__ __forceinline__ float lane_bcast(float v, int lane) {
    return __uint_as_float(__builtin_amdgcn_readlane(__float_as_uint(v), lane));
}

__global__ __launch_bounds__(MLP_BLOCK) void mlp_kernel(
    const float* __restrict__ verts,
    const float* __restrict__ grid_verts,
    const float* __restrict__ grid_feat,
    const float* __restrict__ pre,
    const float* __restrict__ aux,
    const float* __restrict__ cst,
    const int*   __restrict__ knn_idx,
    const float* __restrict__ ew1,
    const float* __restrict__ eg1, const float* __restrict__ ebt1,
    const float* __restrict__ ew2, const float* __restrict__ eb2,
    const float* __restrict__ ow1, const float* __restrict__ ob1,
    const float* __restrict__ og1, const float* __restrict__ obt1,
    const float* __restrict__ ow2, const float* __restrict__ ob2,
    float* __restrict__ out)
{
    __shared__ float s_ew1r[3 * 64];
    __shared__ float s_ew2[64 * 64];
    __shared__ float s_ow1[160 * 64];
    __shared__ float s_ow2[64 * 64];
    __shared__ float s_eg1[64], s_ebt1[64], s_eb2[64];
    __shared__ float s_ob1[64], s_og1[64], s_obt1[64], s_ob2[64];

    const int tid = threadIdx.x;
    for (int t = tid; t < 3 * 64;  t += MLP_BLOCK) s_ew1r[t] = ew1[32 * 64 + t];
    for (int t = tid; t < 64 * 64; t += MLP_BLOCK) s_ew2[t]  = ew2[t];
    for (int t = tid; t < 160 * 64; t += MLP_BLOCK) s_ow1[t] = ow1[t];
    for (int t = tid; t < 64 * 64; t += MLP_BLOCK) s_ow2[t]  = ow2[t];
    if (tid < 64) {
        s_eg1[tid] = eg1[tid];  s_ebt1[tid] = ebt1[tid]; s_eb2[tid] = eb2[tid];
        s_ob1[tid] = ob1[tid];  s_og1[tid] = og1[tid];
        s_obt1[tid] = obt1[tid]; s_ob2[tid] = ob2[tid];
    }
    __syncthreads();

    const int lane = tid & 63;
    const int wave = tid >> 6;
    const int c    = lane;
    const int grp  = blockIdx.x * WPB + wave;
    const int m0   = __builtin_amdgcn_readfirstlane(grp * MT);

    const float Ws0 = cst[0], Ws1 = cst[1], Ws2 = cst[2];
    const float Gxx = cst[3], Gyy = cst[4], Gzz = cst[5];
    const float Gxy = cst[6], Gxz = cst[7], Gyz = cst[8];

    float gvx[MT], gvy[MT], gvz[MT];
#pragma unroll
    for (int p = 0; p < MT; ++p) {
        gvx[p] = grid_verts[(m0 + p) * 3 + 0];
        gvy[p] = grid_verts[(m0 + p) * 3 + 1];
        gvz[p] = grid_verts[(m0 + p) * 3 + 2];
    }

    float gsum[MT];
#pragma unroll
    for (int p = 0; p < MT; ++p) gsum[p] = 0.0f;

    const float inv64 = 1.0f / 64.0f;
    for (int p = 0; p < MT; ++p) {
        for (int j = 0; j < KNN; ++j) {
            int n = __builtin_amdgcn_readfirstlane(knn_idx[(m0 + p) * KNN + j]);
            float S1  = aux[n * 8 + 0], Q = aux[n * 8 + 1];
            float P1x = aux[n * 8 + 2], P1y = aux[n * 8 + 3], P1z = aux[n * 8 + 4];
            float rx = verts[n * 3 + 0] - gvx[p];
            float ry = verts[n * 3 + 1] - gvy[p];
            float rz = verts[n * 3 + 2] - gvz[p];
            float hv = pre[(size_t)n * COUT + c];
            hv = fmaf(rx, s_ew1r[0 * 64 + c], hv);
            hv = fmaf(ry, s_ew1r[1 * 64 + c], hv);
            hv = fmaf(rz, s_ew1r[2 * 64 + c], hv);
            float s1 = S1 + rx * Ws0 + ry * Ws1 + rz * Ws2;
            float s2 = Q + 2.0f * (rx * P1x + ry * P1y + rz * P1z)
                     + rx * rx * Gxx + ry * ry * Gyy + rz * rz * Gzz
                     + 2.0f * (rx * ry * Gxy + rx * rz * Gxz + ry * rz * Gyz);
            float mean = s1 * inv64;
            float var  = s2 * inv64 - mean * mean;
            float xn = (hv - mean) * rsqrtf(var + 1e-5f);
            gsum[p] += gelu_fast(xn * s_eg1[c] + s_ebt1[c]);
        }
    }

    float A[MT];
#pragma unroll
    for (int p = 0; p < MT; ++p) { gsum[p] *= (1.0f / 16.0f); A[p] = s_eb2[c]; }
    for (int jj = 0; jj < 64; ++jj) {
        float w = s_ew2[jj * 64 + c];
#pragma unroll
        for (int p = 0; p < MT; ++p)
            A[p] = fmaf(lane_bcast(gsum[p], jj), w, A[p]);
    }

    float gfa[MT], gfb[MT];
#pragma unroll
    for (int p = 0; p < MT; ++p) {
        gfa[p] = grid_feat[(size_t)(m0 + p) * CPROV + c];
        gfb[p] = grid_feat[(size_t)(m0 + p) * CPROV + 64 + (c & 31)];
    }
    float t1[MT];
#pragma unroll
    for (int p = 0; p < MT; ++p) t1[p] = s_ob1[c];
    for (int jj = 0; jj < 64; ++jj) {
        float w = s_ow1[jj * 64 + c];
#pragma unroll
        for (int p = 0; p < MT; ++p)
            t1[p] = fmaf(lane_bcast(A[p], jj), w, t1[p]);
    }
    for (int i = 0; i < 64; ++i) {
        float w = s_ow1[(64 + i) * 64 + c];
#pragma unroll
        for (int p = 0; p < MT; ++p)
            t1[p] = fmaf(lane_bcast(gfa[p], i), w, t1[p]);
    }
    for (int i = 0; i < 32; ++i) {
        float w = s_ow1[(128 + i) * 64 + c];
#pragma unroll
        for (int p = 0; p < MT; ++p)
            t1[p] = fmaf(lane_bcast(gfb[p], i), w, t1[p]);
    }

#pragma unroll
    for (int p = 0; p < MT; ++p) {
        float x = t1[p];
        float s = x, s2 = x * x;
#pragma unroll
        for (int off = 32; off; off >>= 1) {
            s  += __shfl_xor(s, off);
            s2 += __shfl_xor(s2, off);
        }
        float mean = s * inv64;
        float var  = s2 * inv64 - mean * mean;
        float xn = (x - mean) * rsqrtf(var + 1e-5f);
        t1[p] = gelu_fast(xn * s_og1[c] + s_obt1[c]);
    }

    float o[MT];
#pragma unroll
    for (int p = 0; p < MT; ++p) o[p] = s_ob2[c];
    for (int jj = 0; jj < 64; ++jj) {
        float w = s_ow2[jj * 64 + c];
#pragma unroll
        for (int p = 0; p < MT; ++p)
            o[p] = fmaf(lane_bcast(t1[p], jj), w, o[p]);
    }
#pragma unroll
    for (int p = 0; p < MT; ++p)
        out[(size_t)(m0 + p) * COUT + c] = o[p];
}

// ---------------------------------------------------------------------------
extern "C" void kernel_launch(void* const* d_in, const int* in_sizes, int n_in,
                              void* d_out, int out_size, void* d_ws, size_t ws_size,
                              hipStream_t stream)
{
    const float* verts  = (const float*)d_in[0];
    const float* feats  = (const float*)d_in[1];
    const float* gverts = (const float*)d_in[2];
    const float* gfeat  = (const float*)d_in[3];
    const float* ew1    = (const float*)d_in[4];
    const float* eb1    = (const float*)d_in[5];
    const float* eg1    = (const float*)d_in[6];
    const float* ebt1   = (const float*)d_in[7];
    const float* ew2    = (const float*)d_in[8];
    const float* eb2    = (const float*)d_in[9];
    const float* ow1    = (const float*)d_in[10];
    const float* ob1    = (const float*)d_in[11];
    const float* og1    = (const float*)d_in[12];
    const float* obt1   = (const float*)d_in[13];
    const float* ow2    = (const float*)d_in[14];
    const float* ob2    = (const float*)d_in[15];
    float* out = (float*)d_out;

    char* ws = (char*)d_ws;
    int*    counts  = (int*)(ws + 0);              // 128 KB
    int*    prefix  = (int*)(ws + 131072);         // 32769 ints
    float*  tau     = (float*)(ws + 262152);       // 128 KB
    int*    knn_idx = (int*)(ws + 393224);         // 2 MB -> ends 2490376
    float*  pre     = (float*)(ws + 2490376);      // 2 MB
    float*  aux     = (float*)(ws + 4587528);      // 256 KB
    float*  cst     = (float*)(ws + 4849672);      // 64 B
    float4* vp      = (float4*)(ws + 4849744);     // 128 KB packed verts

    hipMemsetAsync(counts, 0, 32768 * sizeof(int), stream);
    bin_count_kernel<<<NV / 256, 256, 0, stream>>>(verts, counts);
    prefix_kernel<<<1, 1024, 0, stream>>>(counts, prefix);
    radius_kernel<<<NM / 256, 256, 0, stream>>>(gverts, prefix, tau);
    pack_kernel<<<NV / 256, 256, 0, stream>>>(verts, vp);
    knn_block_kernel<<<NM / 64, 1024, 0, stream>>>(vp, gverts, tau, knn_idx);
    pre_edge_kernel<<<(NV * COUT) / 256, 256, 0, stream>>>(feats, ew1, eb1, pre, aux);
    const_kernel<<<1, 64, 0, stream>>>(ew1, cst);
    mlp_kernel<<<NM / (MT * WPB), MLP_BLOCK, 0, stream>>>(verts, gverts, gfeat,
        pre, aux, cst, knn_idx,
        ew1, eg1, ebt1, ew2, eb2, ow1, ob1, og1, obt1, ow2, ob2, out);
}

// Round 6
// 308.356 us; speedup vs baseline: 10.6823x; 1.1151x over previous
//
#include <hip/hip_runtime.h>
#include <cfloat>
#include <cstdint>
#include <cmath>

#define NV    8192
#define NM    32768
#define KNN   16
#define CIN   32
#define COUT  64
#define CPROV 96
#define CAPB  8      // FIFO depth per lane
#define MT    4      // grid points per wave in mlp kernel (R6: 8->4 for 2 blocks/CU)
#define MLP_BLOCK 1024
#define WPB   (MLP_BLOCK/64)

// ===========================================================================
// KNN v3 (spatial): same validated d2/key/gate/FIFO/merge machinery as v2.1
// (R5: PASSED, 119us), but scans only the tau-certified neighborhood:
//   - points scattered into bin order (prefix + atomic cursor); candidates
//     for a query are exactly the cells within Rs = floor(sqrt(tau))+1 of
//     its cell. tau = 3(R+1)^2 is a validated UPPER bound on the 16th-NN
//     d2, and it is never a perfect square => sqrtf floor is safe.
//   - block = one 4x4x4 brick of grid cells (64 queries), 16 waves split
//     the (x,y) columns of the [brick +- Rs] cube; each column's points
//     are a contiguous run [prefix[c+zlo], prefix[c+zhi+1]).
//   - keys carry ORIGINAL vertex indices -> min-16-by-key is scan-order
//     independent -> bit-identical to the full scan (scanned superset
//     contains every point with d2 <= tau, which contains the true top-16;
//     >=16 points with d2 <= tau exist so seeds never survive).
// Candidate count: 8192 -> ~1000-1500 per 64-query block (~6-8x less work).
// ===========================================================================

__device__ __forceinline__ unsigned long long d2key(float d2, unsigned int idx) {
    unsigned int b = __float_as_uint(d2);
    b ^= (b & 0x80000000u) ? 0xFFFFFFFFu : 0x80000000u;  // total-order map
    return ((unsigned long long)b << 32) | idx;
}

__device__ __forceinline__ float key_d2f(unsigned long long key) {
    unsigned int b = (unsigned int)(key >> 32);
    b = (b & 0x80000000u) ? (b ^ 0x80000000u) : ~b;      // inverse map
    return __uint_as_float(b);
}

__device__ __forceinline__ void key_insert(unsigned long long* a,
                                           unsigned long long key) {
    // branchless sorted (ascending) insert-and-drop-max
#pragma unroll
    for (int i = KNN - 1; i >= 1; --i) {
        unsigned long long hi = (a[i-1] > key) ? a[i-1] : key;
        a[i] = (hi < a[i]) ? hi : a[i];
    }
    a[0] = (key < a[0]) ? key : a[0];
}

__device__ __forceinline__ int bin_of(float x) {
    int b = (int)(x * 32.0f);
    return min(31, max(0, b));
}

__global__ __launch_bounds__(256) void bin_count_kernel(
    const float* __restrict__ verts, int* __restrict__ counts)
{
    int v = blockIdx.x * 256 + threadIdx.x;
    int bx = bin_of(verts[v * 3 + 0]);
    int by = bin_of(verts[v * 3 + 1]);
    int bz = bin_of(verts[v * 3 + 2]);
    atomicAdd(&counts[(bx * 32 + by) * 32 + bz], 1);
}

__global__ __launch_bounds__(1024) void prefix_kernel(
    const int* __restrict__ counts, int* __restrict__ prefix)
{
    __shared__ int lds[1024];
    int tid = threadIdx.x;
    int local[32]; int s = 0;
#pragma unroll
    for (int i = 0; i < 32; ++i) { local[i] = counts[tid * 32 + i]; s += local[i]; }
    lds[tid] = s; __syncthreads();
    for (int off = 1; off < 1024; off <<= 1) {
        int v = (tid >= off) ? lds[tid - off] : 0;
        __syncthreads();
        lds[tid] += v;
        __syncthreads();
    }
    int run = lds[tid] - s;
#pragma unroll
    for (int i = 0; i < 32; ++i) { prefix[tid * 32 + i] = run; run += local[i]; }
    if (tid == 1023) prefix[32768] = run;
}

// tau[m] = 3*(R+1)^2 where radius-R cell cube holds >= 16 points (validated R6/R8)
__global__ __launch_bounds__(256) void radius_kernel(
    const float* __restrict__ grid_verts, const int* __restrict__ prefix,
    float* __restrict__ tau)
{
    int m = blockIdx.x * 256 + threadIdx.x;
    int bx = bin_of(grid_verts[m * 3 + 0]);
    int by = bin_of(grid_verts[m * 3 + 1]);
    int bz = bin_of(grid_verts[m * 3 + 2]);
    int R = 1;
    for (; R < 32; ++R) {
        int cnt = 0;
        int xlo = max(0, bx - R), xhi = min(31, bx + R);
        int ylo = max(0, by - R), yhi = min(31, by + R);
        int zlo = max(0, bz - R), zhi = min(31, bz + R);
        for (int x = xlo; x <= xhi; ++x)
            for (int y = ylo; y <= yhi; ++y) {
                int c = (x * 32 + y) * 32;
                cnt += prefix[c + zhi + 1] - prefix[c + zlo];
            }
        if (cnt >= KNN) break;
    }
    float Rp = (float)(R + 1);
    tau[m] = 3.0f * Rp * Rp;
}

// scatter points into bin order; pack (r0,r1,r2,rr) with the EXACT rounding
// sequence of the validated path. bin index reuses r0..r2 ((int)(x*32)
// == bin_of(x) for x>=0).
__global__ __launch_bounds__(256) void scatter_kernel(
    const float* __restrict__ verts, const int* __restrict__ prefix,
    int* __restrict__ cursor, float4* __restrict__ vps, int* __restrict__ vidx)
{
    int v = blockIdx.x * 256 + threadIdx.x;
    float x0 = verts[v * 3 + 0], x1 = verts[v * 3 + 1], x2 = verts[v * 3 + 2];
    float r0 = __fmul_rn(x0, 32.0f);
    float r1 = __fmul_rn(x1, 32.0f);
    float r2 = __fmul_rn(x2, 32.0f);
    float rr = __fadd_rn(__fadd_rn(__fmul_rn(r0, r0), __fmul_rn(r1, r1)),
                         __fmul_rn(r2, r2));
    int bx = min(31, max(0, (int)r0));
    int by = min(31, max(0, (int)r1));
    int bz = min(31, max(0, (int)r2));
    int b = (bx * 32 + by) * 32 + bz;
    int pos = prefix[b] + atomicAdd(&cursor[b], 1);
    vps[pos] = make_float4(r0, r1, r2, rr);
    vidx[pos] = v;
}

#define CSWAP(i, j) { unsigned long long x_ = a[i], y_ = a[j]; \
                      bool c_ = x_ < y_; \
                      a[i] = c_ ? x_ : y_; a[j] = c_ ? y_ : x_; }

__global__ __launch_bounds__(1024, 4) void knn_spatial_kernel(
    const float4* __restrict__ vps,
    const int*    __restrict__ vidx,
    const int*    __restrict__ prefix,
    const float*  __restrict__ grid_verts,
    const float*  __restrict__ tau,
    int* __restrict__ knn_idx)
{
    __shared__ unsigned long long buf[8192];   // 64 KB: scan FIFO, then merge slots
    const int tid  = threadIdx.x;
    const int lane = tid & 63;
    const int w    = tid >> 6;                 // wave id

    // brick decomposition: 8x8x8 bricks of 4x4x4 grid cells; lane -> local cell
    const int bx4 = (blockIdx.x >> 6) * 4;
    const int by4 = ((blockIdx.x >> 3) & 7) * 4;
    const int bz4 = (blockIdx.x & 7) * 4;
    const int lx = lane >> 4, ly = (lane >> 2) & 3, lz = lane & 3;
    const int m = ((bx4 + lx) * 32 + (by4 + ly)) * 32 + (bz4 + lz);

    const float q0 = __fmul_rn(grid_verts[m * 3 + 0], 32.0f);
    const float q1 = __fmul_rn(grid_verts[m * 3 + 1], 32.0f);
    const float q2 = __fmul_rn(grid_verts[m * 3 + 2], 32.0f);
    const float qq = __fadd_rn(__fadd_rn(__fmul_rn(q0, q0), __fmul_rn(q1, q1)),
                               __fmul_rn(q2, q2));

    const float tm = tau[m];
    // seed = key(bound), idx 0; bound > all golden top-16 d2 (validated margin)
    const float bound = tm + 0.13f;
    unsigned int bb = __float_as_uint(bound) ^ 0x80000000u;  // bound > 0
    const unsigned long long seed = ((unsigned long long)bb << 32);

    unsigned long long a[KNN];
#pragma unroll
    for (int s = 0; s < KNN; ++s) a[s] = seed;
    float gd = bound;      // d2-domain gate = d2 part of a[15]
    int cnt = 0;

    // scan radius: all points with d2 <= tau lie within rs cells per axis.
    // block-uniform max over the 64 queries (identical in every wave).
    int rs = (int)sqrtf(tm) + 1;
#pragma unroll
    for (int off = 32; off; off >>= 1) rs = max(rs, __shfl_xor(rs, off));

    const int xlo = max(0, bx4 - rs), xhi = min(31, bx4 + 3 + rs);
    const int ylo = max(0, by4 - rs), yhi = min(31, by4 + 3 + rs);
    const int zlo = max(0, bz4 - rs), zhi = min(31, bz4 + 3 + rs);
    const int ny = yhi - ylo + 1;
    const int npair = (xhi - xlo + 1) * ny;

    for (int pi = w; pi < npair; pi += 16) {
        const int x = xlo + pi / ny;
        const int y = ylo + pi % ny;
        const int c = (x * 32 + y) * 32;
        const int pstart = prefix[c + zlo];
        const int pend   = prefix[c + zhi + 1];
        for (int p = pstart; p < pend; ++p) {
            float4 v = vps[p];
            float dot = fmaf(q2, v.z, fmaf(q1, v.y, __fmul_rn(q0, v.x)));
            // == (qq+rr) - 2*dot bit-exactly (2*dot exact)
            float d2 = fmaf(-2.0f, dot, __fadd_rn(qq, v.w));
            if (d2 <= gd) {     // conservative: ties resolved by insert
                unsigned long long key = d2key(d2, (unsigned int)vidx[p]);
                if (cnt < CAPB) { buf[cnt * 1024 + tid] = key; ++cnt; }
                else {  // rare overflow: exact direct insert, tighten gate
                    key_insert(a, key);
                    gd = key_d2f(a[KNN - 1]);
                }
            }
        }
        // drain private FIFO (lane-private columns; no barrier needed)
        int mx = cnt;
#pragma unroll
        for (int off = 32; off; off >>= 1) mx = max(mx, __shfl_xor(mx, off));
        for (int k = 0; k < mx; ++k) {
            unsigned long long key = (k < cnt) ? buf[k * 1024 + tid] : ~0ULL;
            key_insert(a, key);
        }
        if (mx) gd = key_d2f(a[KNN - 1]);
        cnt = 0;
    }

    // ---- cross-wave merge tree: 16 sorted lists -> 1, bitonic in registers ----
    // round half: waves [half,2*half) publish, waves [0,half) merge slot w.
    for (int half = 8; half >= 1; half >>= 1) {
        __syncthreads();                       // prior reads done before overwrite
        if (w >= half && w < 2 * half) {
            unsigned long long* dst = &buf[(w - half) * 1024];
#pragma unroll
            for (int s = 0; s < KNN; ++s) dst[s * 64 + lane] = a[s];
        }
        __syncthreads();
        if (w < half) {
            const unsigned long long* src = &buf[w * 1024];
            // L[i] = min(a[i], b[15-i]) : 16 smallest of union, bitonic
#pragma unroll
            for (int i = 0; i < KNN; ++i) {
                unsigned long long b = src[(KNN - 1 - i) * 64 + lane];
                a[i] = (b < a[i]) ? b : a[i];
            }
            // clean bitonic-16 -> ascending (static indices, no scratch)
            CSWAP(0, 8)  CSWAP(1, 9)  CSWAP(2, 10) CSWAP(3, 11)
            CSWAP(4, 12) CSWAP(5, 13) CSWAP(6, 14) CSWAP(7, 15)
            CSWAP(0, 4)  CSWAP(1, 5)  CSWAP(2, 6)  CSWAP(3, 7)
            CSWAP(8, 12) CSWAP(9, 13) CSWAP(10, 14) CSWAP(11, 15)
            CSWAP(0, 2)  CSWAP(1, 3)  CSWAP(4, 6)  CSWAP(5, 7)
            CSWAP(8, 10) CSWAP(9, 11) CSWAP(12, 14) CSWAP(13, 15)
            CSWAP(0, 1)  CSWAP(2, 3)  CSWAP(4, 5)  CSWAP(6, 7)
            CSWAP(8, 9)  CSWAP(10, 11) CSWAP(12, 13) CSWAP(14, 15)
        }
    }

    if (w == 0) {
#pragma unroll
        for (int s = 0; s < KNN; ++s)
            knn_idx[m * KNN + s] = (int)(a[s] & 0xFFFFFFFFu);
    }
}

// ===========================================================================
// MLP precompute (unchanged — passed)
// ===========================================================================

__global__ void const_kernel(const float* __restrict__ ew1, float* __restrict__ cst)
{
    int c = threadIdx.x;   // 64 threads
    float w0 = ew1[32 * 64 + c], w1 = ew1[33 * 64 + c], w2 = ew1[34 * 64 + c];
    float v[9] = { w0, w1, w2, w0*w0, w1*w1, w2*w2, w0*w1, w0*w2, w1*w2 };
#pragma unroll
    for (int k = 0; k < 9; ++k) {
#pragma unroll
        for (int off = 32; off; off >>= 1) v[k] += __shfl_xor(v[k], off);
    }
    if (c == 0) {
        cst[0] = v[0]; cst[1] = v[1]; cst[2] = v[2];
        cst[3] = v[3]; cst[4] = v[4]; cst[5] = v[5];
        cst[6] = v[6]; cst[7] = v[7]; cst[8] = v[8];
    }
}

__global__ __launch_bounds__(256) void pre_edge_kernel(
    const float* __restrict__ feats, const float* __restrict__ ew1,
    const float* __restrict__ eb1, float* __restrict__ pre,
    float* __restrict__ aux)
{
    int t = blockIdx.x * 256 + threadIdx.x;
    int n = t >> 6, c = t & 63;
    float acc = eb1[c];
#pragma unroll
    for (int i = 0; i < CIN; ++i)
        acc = fmaf(feats[n * CIN + i], ew1[i * COUT + c], acc);
    pre[t] = acc;

    float w0 = ew1[32 * 64 + c], w1 = ew1[33 * 64 + c], w2 = ew1[34 * 64 + c];
    float v[5] = { acc, acc * acc, acc * w0, acc * w1, acc * w2 };
#pragma unroll
    for (int k = 0; k < 5; ++k) {
#pragma unroll
        for (int off = 32; off; off >>= 1) v[k] += __shfl_xor(v[k], off);
    }
    if (c == 0) {
        aux[n * 8 + 0] = v[0]; aux[n * 8 + 1] = v[1];
        aux[n * 8 + 2] = v[2]; aux[n * 8 + 3] = v[3]; aux[n * 8 + 4] = v[4];
    }
}

// ===========================================================================
// Main MLP (algorithm unchanged — passed; R6: MT 8->4 so 512 blocks give
// 2 blocks/CU = 32 waves/CU instead of 1 block/CU = 16 = 50% hard cap)
// ===========================================================================
__device__ __forceinline__ float gelu_fast(float x) {
    float t = fmaf(0.044715f, x * x, 1.0f);
    float u = 0.7978845608028654f * x * t;
    float e = __expf(-2.0f * u);
    return x * __builtin_amdgcn_rcpf(1.0f + e);
}

__device__ __forceinline__ float lane_bcast(float v, int lane) {
    return __uint_as_float(__builtin_amdgcn_readlane(__float_as_uint(v), lane));
}

__global__ __launch_bounds__(MLP_BLOCK) void mlp_kernel(
    const float* __restrict__ verts,
    const float* __restrict__ grid_verts,
    const float* __restrict__ grid_feat,
    const float* __restrict__ pre,
    const float* __restrict__ aux,
    const float* __restrict__ cst,
    const int*   __restrict__ knn_idx,
    const float* __restrict__ ew1,
    const float* __restrict__ eg1, const float* __restrict__ ebt1,
    const float* __restrict__ ew2, const float* __restrict__ eb2,
    const float* __restrict__ ow1, const float* __restrict__ ob1,
    const float* __restrict__ og1, const float* __restrict__ obt1,
    const float* __restrict__ ow2, const float* __restrict__ ob2,
    float* __restrict__ out)
{
    __shared__ float s_ew1r[3 * 64];
    __shared__ float s_ew2[64 * 64];
    __shared__ float s_ow1[160 * 64];
    __shared__ float s_ow2[64 * 64];
    __shared__ float s_eg1[64], s_ebt1[64], s_eb2[64];
    __shared__ float s_ob1[64], s_og1[64], s_obt1[64], s_ob2[64];

    const int tid = threadIdx.x;
    for (int t = tid; t < 3 * 64;  t += MLP_BLOCK) s_ew1r[t] = ew1[32 * 64 + t];
    for (int t = tid; t < 64 * 64; t += MLP_BLOCK) s_ew2[t]  = ew2[t];
    for (int t = tid; t < 160 * 64; t += MLP_BLOCK) s_ow1[t] = ow1[t];
    for (int t = tid; t < 64 * 64; t += MLP_BLOCK) s_ow2[t]  = ow2[t];
    if (tid < 64) {
        s_eg1[tid] = eg1[tid];  s_ebt1[tid] = ebt1[tid]; s_eb2[tid] = eb2[tid];
        s_ob1[tid] = ob1[tid];  s_og1[tid] = og1[tid];
        s_obt1[tid] = obt1[tid]; s_ob2[tid] = ob2[tid];
    }
    __syncthreads();

    const int lane = tid & 63;
    const int wave = tid >> 6;
    const int c    = lane;
    const int grp  = blockIdx.x * WPB + wave;
    const int m0   = __builtin_amdgcn_readfirstlane(grp * MT);

    const float Ws0 = cst[0], Ws1 = cst[1], Ws2 = cst[2];
    const float Gxx = cst[3], Gyy = cst[4], Gzz = cst[5];
    const float Gxy = cst[6], Gxz = cst[7], Gyz = cst[8];

    float gvx[MT], gvy[MT], gvz[MT];
#pragma unroll
    for (int p = 0; p < MT; ++p) {
        gvx[p] = grid_verts[(m0 + p) * 3 + 0];
        gvy[p] = grid_verts[(m0 + p) * 3 + 1];
        gvz[p] = grid_verts[(m0 + p) * 3 + 2];
    }

    float gsum[MT];
#pragma unroll
    for (int p = 0; p < MT; ++p) gsum[p] = 0.0f;

    const float inv64 = 1.0f / 64.0f;
    for (int p = 0; p < MT; ++p) {
        for (int j = 0; j < KNN; ++j) {
            int n = __builtin_amdgcn_readfirstlane(knn_idx[(m0 + p) * KNN + j]);
            float S1  = aux[n * 8 + 0], Q = aux[n * 8 + 1];
            float P1x = aux[n * 8 + 2], P1y = aux[n * 8 + 3], P1z = aux[n * 8 + 4];
            float rx = verts[n * 3 + 0] - gvx[p];
            float ry = verts[n * 3 + 1] - gvy[p];
            float rz = verts[n * 3 + 2] - gvz[p];
            float hv = pre[(size_t)n * COUT + c];
            hv = fmaf(rx, s_ew1r[0 * 64 + c], hv);
            hv = fmaf(ry, s_ew1r[1 * 64 + c], hv);
            hv = fmaf(rz, s_ew1r[2 * 64 + c], hv);
            float s1 = S1 + rx * Ws0 + ry * Ws1 + rz * Ws2;
            float s2 = Q + 2.0f * (rx * P1x + ry * P1y + rz * P1z)
                     + rx * rx * Gxx + ry * ry * Gyy + rz * rz * Gzz
                     + 2.0f * (rx * ry * Gxy + rx * rz * Gxz + ry * rz * Gyz);
            float mean = s1 * inv64;
            float var  = s2 * inv64 - mean * mean;
            float xn = (hv - mean) * rsqrtf(var + 1e-5f);
            gsum[p] += gelu_fast(xn * s_eg1[c] + s_ebt1[c]);
        }
    }

    float A[MT];
#pragma unroll
    for (int p = 0; p < MT; ++p) { gsum[p] *= (1.0f / 16.0f); A[p] = s_eb2[c]; }
    for (int jj = 0; jj < 64; ++jj) {
        float w = s_ew2[jj * 64 + c];
#pragma unroll
        for (int p = 0; p < MT; ++p)
            A[p] = fmaf(lane_bcast(gsum[p], jj), w, A[p]);
    }

    float gfa[MT], gfb[MT];
#pragma unroll
    for (int p = 0; p < MT; ++p) {
        gfa[p] = grid_feat[(size_t)(m0 + p) * CPROV + c];
        gfb[p] = grid_feat[(size_t)(m0 + p) * CPROV + 64 + (c & 31)];
    }
    float t1[MT];
#pragma unroll
    for (int p = 0; p < MT; ++p) t1[p] = s_ob1[c];
    for (int jj = 0; jj < 64; ++jj) {
        float w = s_ow1[jj * 64 + c];
#pragma unroll
        for (int p = 0; p < MT; ++p)
            t1[p] = fmaf(lane_bcast(A[p], jj), w, t1[p]);
    }
    for (int i = 0; i < 64; ++i) {
        float w = s_ow1[(64 + i) * 64 + c];
#pragma unroll
        for (int p = 0; p < MT; ++p)
            t1[p] = fmaf(lane_bcast(gfa[p], i), w, t1[p]);
    }
    for (int i = 0; i < 32; ++i) {
        float w = s_ow1[(128 + i) * 64 + c];
#pragma unroll
        for (int p = 0; p < MT; ++p)
            t1[p] = fmaf(lane_bcast(gfb[p], i), w, t1[p]);
    }

#pragma unroll
    for (int p = 0; p < MT; ++p) {
        float x = t1[p];
        float s = x, s2 = x * x;
#pragma unroll
        for (int off = 32; off; off >>= 1) {
            s  += __shfl_xor(s, off);
            s2 += __shfl_xor(s2, off);
        }
        float mean = s * inv64;
        float var  = s2 * inv64 - mean * mean;
        float xn = (x - mean) * rsqrtf(var + 1e-5f);
        t1[p] = gelu_fast(xn * s_og1[c] + s_obt1[c]);
    }

    float o[MT];
#pragma unroll
    for (int p = 0; p < MT; ++p) o[p] = s_ob2[c];
    for (int jj = 0; jj < 64; ++jj) {
        float w = s_ow2[jj * 64 + c];
#pragma unroll
        for (int p = 0; p < MT; ++p)
            o[p] = fmaf(lane_bcast(t1[p], jj), w, o[p]);
    }
#pragma unroll
    for (int p = 0; p < MT; ++p)
        out[(size_t)(m0 + p) * COUT + c] = o[p];
}

// ---------------------------------------------------------------------------
extern "C" void kernel_launch(void* const* d_in, const int* in_sizes, int n_in,
                              void* d_out, int out_size, void* d_ws, size_t ws_size,
                              hipStream_t stream)
{
    const float* verts  = (const float*)d_in[0];
    const float* feats  = (const float*)d_in[1];
    const float* gverts = (const float*)d_in[2];
    const float* gfeat  = (const float*)d_in[3];
    const float* ew1    = (const float*)d_in[4];
    const float* eb1    = (const float*)d_in[5];
    const float* eg1    = (const float*)d_in[6];
    const float* ebt1   = (const float*)d_in[7];
    const float* ew2    = (const float*)d_in[8];
    const float* eb2    = (const float*)d_in[9];
    const float* ow1    = (const float*)d_in[10];
    const float* ob1    = (const float*)d_in[11];
    const float* og1    = (const float*)d_in[12];
    const float* obt1   = (const float*)d_in[13];
    const float* ow2    = (const float*)d_in[14];
    const float* ob2    = (const float*)d_in[15];
    float* out = (float*)d_out;

    char* ws = (char*)d_ws;
    int*    counts  = (int*)(ws + 0);              // 128 KB
    int*    cursor  = (int*)(ws + 131072);         // 128 KB (memset with counts)
    int*    prefix  = (int*)(ws + 262144);         // 32769 ints -> ends 393220
    float*  tau     = (float*)(ws + 393224);       // 128 KB -> ends 524296
    int*    knn_idx = (int*)(ws + 524296);         // 2 MB -> ends 2621448
    float4* vps     = (float4*)(ws + 2621456);     // 128 KB (16-aligned) -> 2752528
    int*    vidx    = (int*)(ws + 2752528);        // 32 KB -> ends 2785296
    float*  pre     = (float*)(ws + 2785296);      // 2 MB -> ends 4882448
    float*  aux     = (float*)(ws + 4882448);      // 256 KB -> ends 5144592
    float*  cst     = (float*)(ws + 5144592);      // 64 B

    hipMemsetAsync(counts, 0, 262144, stream);     // counts + cursor
    bin_count_kernel<<<NV / 256, 256, 0, stream>>>(verts, counts);
    prefix_kernel<<<1, 1024, 0, stream>>>(counts, prefix);
    radius_kernel<<<NM / 256, 256, 0, stream>>>(gverts, prefix, tau);
    scatter_kernel<<<NV / 256, 256, 0, stream>>>(verts, prefix, cursor, vps, vidx);
    knn_spatial_kernel<<<NM / 64, 1024, 0, stream>>>(vps, vidx, prefix, gverts, tau, knn_idx);
    pre_edge_kernel<<<(NV * COUT) / 256, 256, 0, stream>>>(feats, ew1, eb1, pre, aux);
    const_kernel<<<1, 64, 0, stream>>>(ew1, cst);
    mlp_kernel<<<NM / (MT * WPB), MLP_BLOCK, 0, stream>>>(verts, gverts, gfeat,
        pre, aux, cst, knn_idx,
        ew1, eg1, ebt1, ew2, eb2, ow1, ob1, og1, obt1, ow2, ob2, out);
}

// Round 7
// 286.376 us; speedup vs baseline: 11.5021x; 1.0767x over previous
//
#include <hip/hip_runtime.h>
#include <cfloat>
#include <cstdint>
#include <cmath>

#define NV    8192
#define NM    32768
#define KNN   16
#define CIN   32
#define COUT  64
#define CPROV 96
#define CAPB  8      // FIFO depth per lane
#define MT    4      // grid points per wave in mlp kernel (R6: validated, 2 blocks/CU)
#define MLP_BLOCK 1024
#define WPB   (MLP_BLOCK/64)

// ===========================================================================
// KNN v3.1 (sphere-clipped spatial scan). R6 post-mortem: cube scan visited
// ~1024 pts/block (16^3 cells) and per-column drains cost ~60 VALU/key.
// This round: per-column z-clip by the remaining distance budget --
//   column (x,y): mdx = max(0, celldist_x(brick,x) - 1), same for y;
//   rem = taumax - mdx^2 - mdy^2; skip column if rem < 0, else z-cells
//   within zrc = floor(sqrt(rem))+1 of the brick. All quantities are small
//   integers, exact in fp32; the clipped set is a conservative superset of
//   every {d2 <= tau[q]} ball => results remain bit-identical.
// Also: clamp pstart/pend (and rs/zrc/x) so worst-case work is bounded even
// if prefix/tau are transiently poisoned (R6 saw one 40 ms outlier dispatch
// with garbage-sized runs); and incremental (x,y) walk (ny >= 8 always =>
// <= 2 carries) replaces per-column integer div/mod.
// ===========================================================================

__device__ __forceinline__ unsigned long long d2key(float d2, unsigned int idx) {
    unsigned int b = __float_as_uint(d2);
    b ^= (b & 0x80000000u) ? 0xFFFFFFFFu : 0x80000000u;  // total-order map
    return ((unsigned long long)b << 32) | idx;
}

__device__ __forceinline__ float key_d2f(unsigned long long key) {
    unsigned int b = (unsigned int)(key >> 32);
    b = (b & 0x80000000u) ? (b ^ 0x80000000u) : ~b;      // inverse map
    return __uint_as_float(b);
}

__device__ __forceinline__ void key_insert(unsigned long long* a,
                                           unsigned long long key) {
    // branchless sorted (ascending) insert-and-drop-max
#pragma unroll
    for (int i = KNN - 1; i >= 1; --i) {
        unsigned long long hi = (a[i-1] > key) ? a[i-1] : key;
        a[i] = (hi < a[i]) ? hi : a[i];
    }
    a[0] = (key < a[0]) ? key : a[0];
}

__device__ __forceinline__ int bin_of(float x) {
    int b = (int)(x * 32.0f);
    return min(31, max(0, b));
}

__global__ __launch_bounds__(256) void bin_count_kernel(
    const float* __restrict__ verts, int* __restrict__ counts)
{
    int v = blockIdx.x * 256 + threadIdx.x;
    int bx = bin_of(verts[v * 3 + 0]);
    int by = bin_of(verts[v * 3 + 1]);
    int bz = bin_of(verts[v * 3 + 2]);
    atomicAdd(&counts[(bx * 32 + by) * 32 + bz], 1);
}

__global__ __launch_bounds__(1024) void prefix_kernel(
    const int* __restrict__ counts, int* __restrict__ prefix)
{
    __shared__ int lds[1024];
    int tid = threadIdx.x;
    int local[32]; int s = 0;
#pragma unroll
    for (int i = 0; i < 32; ++i) { local[i] = counts[tid * 32 + i]; s += local[i]; }
    lds[tid] = s; __syncthreads();
    for (int off = 1; off < 1024; off <<= 1) {
        int v = (tid >= off) ? lds[tid - off] : 0;
        __syncthreads();
        lds[tid] += v;
        __syncthreads();
    }
    int run = lds[tid] - s;
#pragma unroll
    for (int i = 0; i < 32; ++i) { prefix[tid * 32 + i] = run; run += local[i]; }
    if (tid == 1023) prefix[32768] = run;
}

// tau[m] = 3*(R+1)^2 where radius-R cell cube holds >= 16 points (validated R6/R8)
__global__ __launch_bounds__(256) void radius_kernel(
    const float* __restrict__ grid_verts, const int* __restrict__ prefix,
    float* __restrict__ tau)
{
    int m = blockIdx.x * 256 + threadIdx.x;
    int bx = bin_of(grid_verts[m * 3 + 0]);
    int by = bin_of(grid_verts[m * 3 + 1]);
    int bz = bin_of(grid_verts[m * 3 + 2]);
    int R = 1;
    for (; R < 32; ++R) {
        int cnt = 0;
        int xlo = max(0, bx - R), xhi = min(31, bx + R);
        int ylo = max(0, by - R), yhi = min(31, by + R);
        int zlo = max(0, bz - R), zhi = min(31, bz + R);
        for (int x = xlo; x <= xhi; ++x)
            for (int y = ylo; y <= yhi; ++y) {
                int c = (x * 32 + y) * 32;
                cnt += prefix[c + zhi + 1] - prefix[c + zlo];
            }
        if (cnt >= KNN) break;
    }
    float Rp = (float)(R + 1);
    tau[m] = 3.0f * Rp * Rp;
}

// scatter points into bin order; pack (r0,r1,r2,rr) with the EXACT rounding
// sequence of the validated path. bin index reuses r0..r2 ((int)(x*32)
// == bin_of(x) for x>=0).
__global__ __launch_bounds__(256) void scatter_kernel(
    const float* __restrict__ verts, const int* __restrict__ prefix,
    int* __restrict__ cursor, float4* __restrict__ vps, int* __restrict__ vidx)
{
    int v = blockIdx.x * 256 + threadIdx.x;
    float x0 = verts[v * 3 + 0], x1 = verts[v * 3 + 1], x2 = verts[v * 3 + 2];
    float r0 = __fmul_rn(x0, 32.0f);
    float r1 = __fmul_rn(x1, 32.0f);
    float r2 = __fmul_rn(x2, 32.0f);
    float rr = __fadd_rn(__fadd_rn(__fmul_rn(r0, r0), __fmul_rn(r1, r1)),
                         __fmul_rn(r2, r2));
    int bx = min(31, max(0, (int)r0));
    int by = min(31, max(0, (int)r1));
    int bz = min(31, max(0, (int)r2));
    int b = (bx * 32 + by) * 32 + bz;
    int pos = prefix[b] + atomicAdd(&cursor[b], 1);
    vps[pos] = make_float4(r0, r1, r2, rr);
    vidx[pos] = v;
}

#define CSWAP(i, j) { unsigned long long x_ = a[i], y_ = a[j]; \
                      bool c_ = x_ < y_; \
                      a[i] = c_ ? x_ : y_; a[j] = c_ ? y_ : x_; }

__global__ __launch_bounds__(1024, 4) void knn_spatial_kernel(
    const float4* __restrict__ vps,
    const int*    __restrict__ vidx,
    const int*    __restrict__ prefix,
    const float*  __restrict__ grid_verts,
    const float*  __restrict__ tau,
    int* __restrict__ knn_idx)
{
    __shared__ unsigned long long buf[8192];   // 64 KB: scan FIFO, then merge slots
    const int tid  = threadIdx.x;
    const int lane = tid & 63;
    const int w    = tid >> 6;                 // wave id

    // brick decomposition: 8x8x8 bricks of 4x4x4 grid cells; lane -> local cell
    const int bx4 = (blockIdx.x >> 6) * 4;
    const int by4 = ((blockIdx.x >> 3) & 7) * 4;
    const int bz4 = (blockIdx.x & 7) * 4;
    const int lx = lane >> 4, ly = (lane >> 2) & 3, lz = lane & 3;
    const int m = ((bx4 + lx) * 32 + (by4 + ly)) * 32 + (bz4 + lz);

    const float q0 = __fmul_rn(grid_verts[m * 3 + 0], 32.0f);
    const float q1 = __fmul_rn(grid_verts[m * 3 + 1], 32.0f);
    const float q2 = __fmul_rn(grid_verts[m * 3 + 2], 32.0f);
    const float qq = __fadd_rn(__fadd_rn(__fmul_rn(q0, q0), __fmul_rn(q1, q1)),
                               __fmul_rn(q2, q2));

    const float tm = tau[m];
    // seed = key(bound), idx 0; bound > all golden top-16 d2 (validated margin)
    const float bound = tm + 0.13f;
    unsigned int bb = __float_as_uint(bound) ^ 0x80000000u;  // bound > 0
    const unsigned long long seed = ((unsigned long long)bb << 32);

    unsigned long long a[KNN];
#pragma unroll
    for (int s = 0; s < KNN; ++s) a[s] = seed;
    float gd = bound;      // d2-domain gate = d2 part of a[15]
    int cnt = 0;

    // block-uniform tau max (identical in every wave: lane->query map is
    // wave-independent)
    float tmax = tm;
#pragma unroll
    for (int off = 32; off; off >>= 1)
        tmax = fmaxf(tmax, __uint_as_float(__shfl_xor(__float_as_uint(tmax), off)));

    int rs = (int)sqrtf(tmax) + 1;
    rs = min(31, max(1, rs));                  // poison-bounded
    const int xlo = max(0, bx4 - rs), xhi = min(31, bx4 + 3 + rs);
    const int ylo = max(0, by4 - rs), yhi = min(31, by4 + 3 + rs);
    const int ny = yhi - ylo + 1;
    const int npair = (xhi - xlo + 1) * ny;

    int xx = xlo + w / ny;                     // w < 16, ny >= 8 on clean data
    int yy = ylo + w % ny;
    for (int pi = w; pi < npair; pi += 16) {
        // per-column distance budget (sphere clip); all-int fp32 => exact
        int cdx = max(0, max(bx4 - xx, xx - bx4 - 3));
        int cdy = max(0, max(by4 - yy, yy - by4 - 3));
        int mdx = max(0, cdx - 1), mdy = max(0, cdy - 1);
        float rem = tmax - (float)(mdx * mdx + mdy * mdy);
        if (rem >= 0.0f) {
            int zrc = (int)sqrtf(rem) + 1;
            zrc = min(31, max(0, zrc));        // poison-bounded
            const int zl = max(0, bz4 - zrc), zh = min(31, bz4 + 3 + zrc);
            const int cxx = min(xx, 31);       // poison-bounded
            const int c = (cxx * 32 + yy) * 32;
            int pstart = prefix[c + zl];
            int pend   = prefix[c + zh + 1];
            pstart = min(max(pstart, 0), NV);  // poison-bounded
            pend   = min(max(pend, pstart), NV);
            for (int p = pstart; p < pend; ++p) {
                float4 v = vps[p];
                float dot = fmaf(q2, v.z, fmaf(q1, v.y, __fmul_rn(q0, v.x)));
                // == (qq+rr) - 2*dot bit-exactly (2*dot exact)
                float d2 = fmaf(-2.0f, dot, __fadd_rn(qq, v.w));
                if (d2 <= gd) {     // conservative: ties resolved by insert
                    unsigned long long key = d2key(d2, (unsigned int)vidx[p]);
                    if (cnt < CAPB) { buf[cnt * 1024 + tid] = key; ++cnt; }
                    else {  // rare overflow: exact direct insert, tighten gate
                        key_insert(a, key);
                        gd = key_d2f(a[KNN - 1]);
                    }
                }
            }
            // drain private FIFO (lane-private columns; no barrier needed)
            int mx = cnt;
#pragma unroll
            for (int off = 32; off; off >>= 1) mx = max(mx, __shfl_xor(mx, off));
            for (int k = 0; k < mx; ++k) {
                unsigned long long key = (k < cnt) ? buf[k * 1024 + tid] : ~0ULL;
                key_insert(a, key);
            }
            if (mx) gd = key_d2f(a[KNN - 1]);
            cnt = 0;
        }
        // advance (xx,yy) by 16 columns; ny >= 8 => at most 2 carries
        yy += 16;
        if (yy > yhi) { yy -= ny; ++xx; }
        if (yy > yhi) { yy -= ny; ++xx; }
    }

    // ---- cross-wave merge tree: 16 sorted lists -> 1, bitonic in registers ----
    // round half: waves [half,2*half) publish, waves [0,half) merge slot w.
    for (int half = 8; half >= 1; half >>= 1) {
        __syncthreads();                       // prior reads done before overwrite
        if (w >= half && w < 2 * half) {
            unsigned long long* dst = &buf[(w - half) * 1024];
#pragma unroll
            for (int s = 0; s < KNN; ++s) dst[s * 64 + lane] = a[s];
        }
        __syncthreads();
        if (w < half) {
            const unsigned long long* src = &buf[w * 1024];
            // L[i] = min(a[i], b[15-i]) : 16 smallest of union, bitonic
#pragma unroll
            for (int i = 0; i < KNN; ++i) {
                unsigned long long b = src[(KNN - 1 - i) * 64 + lane];
                a[i] = (b < a[i]) ? b : a[i];
            }
            // clean bitonic-16 -> ascending (static indices, no scratch)
            CSWAP(0, 8)  CSWAP(1, 9)  CSWAP(2, 10) CSWAP(3, 11)
            CSWAP(4, 12) CSWAP(5, 13) CSWAP(6, 14) CSWAP(7, 15)
            CSWAP(0, 4)  CSWAP(1, 5)  CSWAP(2, 6)  CSWAP(3, 7)
            CSWAP(8, 12) CSWAP(9, 13) CSWAP(10, 14) CSWAP(11, 15)
            CSWAP(0, 2)  CSWAP(1, 3)  CSWAP(4, 6)  CSWAP(5, 7)
            CSWAP(8, 10) CSWAP(9, 11) CSWAP(12, 14) CSWAP(13, 15)
            CSWAP(0, 1)  CSWAP(2, 3)  CSWAP(4, 5)  CSWAP(6, 7)
            CSWAP(8, 9)  CSWAP(10, 11) CSWAP(12, 13) CSWAP(14, 15)
        }
    }

    if (w == 0) {
#pragma unroll
        for (int s = 0; s < KNN; ++s)
            knn_idx[m * KNN + s] = (int)(a[s] & 0xFFFFFFFFu);
    }
}

// ===========================================================================
// MLP precompute (unchanged — passed)
// ===========================================================================

__global__ void const_kernel(const float* __restrict__ ew1, float* __restrict__ cst)
{
    int c = threadIdx.x;   // 64 threads
    float w0 = ew1[32 * 64 + c], w1 = ew1[33 * 64 + c], w2 = ew1[34 * 64 + c];
    float v[9] = { w0, w1, w2, w0*w0, w1*w1, w2*w2, w0*w1, w0*w2, w1*w2 };
#pragma unroll
    for (int k = 0; k < 9; ++k) {
#pragma unroll
        for (int off = 32; off; off >>= 1) v[k] += __shfl_xor(v[k], off);
    }
    if (c == 0) {
        cst[0] = v[0]; cst[1] = v[1]; cst[2] = v[2];
        cst[3] = v[3]; cst[4] = v[4]; cst[5] = v[5];
        cst[6] = v[6]; cst[7] = v[7]; cst[8] = v[8];
    }
}

__global__ __launch_bounds__(256) void pre_edge_kernel(
    const float* __restrict__ feats, const float* __restrict__ ew1,
    const float* __restrict__ eb1, float* __restrict__ pre,
    float* __restrict__ aux)
{
    int t = blockIdx.x * 256 + threadIdx.x;
    int n = t >> 6, c = t & 63;
    float acc = eb1[c];
#pragma unroll
    for (int i = 0; i < CIN; ++i)
        acc = fmaf(feats[n * CIN + i], ew1[i * COUT + c], acc);
    pre[t] = acc;

    float w0 = ew1[32 * 64 + c], w1 = ew1[33 * 64 + c], w2 = ew1[34 * 64 + c];
    float v[5] = { acc, acc * acc, acc * w0, acc * w1, acc * w2 };
#pragma unroll
    for (int k = 0; k < 5; ++k) {
#pragma unroll
        for (int off = 32; off; off >>= 1) v[k] += __shfl_xor(v[k], off);
    }
    if (c == 0) {
        aux[n * 8 + 0] = v[0]; aux[n * 8 + 1] = v[1];
        aux[n * 8 + 2] = v[2]; aux[n * 8 + 3] = v[3]; aux[n * 8 + 4] = v[4];
    }
}

// ===========================================================================
// Main MLP. R7: LN statistics (s1,s2,mean,irstd) are lane-invariant -- the
// 64 (p,j) combos map 1:1 onto 64 lanes. Setup pass computes each combo's
// rx,ry,rz,mean,irstd ONCE (bit-identical expressions), main loop fetches
// them via immediate-index v_readlane (5 ops vs ~28 recompute per (p,j)).
// ===========================================================================
__device__ __forceinline__ float gelu_fast(float x) {
    float t = fmaf(0.044715f, x * x, 1.0f);
    float u = 0.7978845608028654f * x * t;
    float e = __expf(-2.0f * u);
    return x * __builtin_amdgcn_rcpf(1.0f + e);
}

__device__ __forceinline__ float lane_bcast(float v, int lane) {
    return __uint_as_float(__builtin_amdgcn_readlane(__float_as_uint(v), lane));
}

__global__ __launch_bounds__(MLP_BLOCK) void mlp_kernel(
    const float* __restrict__ verts,
    const float* __restrict__ grid_verts,
    const float* __restrict__ grid_feat,
    const float* __restrict__ pre,
    const float* __restrict__ aux,
    const float* __restrict__ cst,
    const int*   __restrict__ knn_idx,
    const float* __restrict__ ew1,
    const float* __restrict__ eg1, const float* __restrict__ ebt1,
    const float* __restrict__ ew2, const float* __restrict__ eb2,
    const float* __restrict__ ow1, const float* __restrict__ ob1,
    const float* __restrict__ og1, const float* __restrict__ obt1,
    const float* __restrict__ ow2, const float* __restrict__ ob2,
    float* __restrict__ out)
{
    __shared__ float s_ew1r[3 * 64];
    __shared__ float s_ew2[64 * 64];
    __shared__ float s_ow1[160 * 64];
    __shared__ float s_ow2[64 * 64];
    __shared__ float s_eg1[64], s_ebt1[64], s_eb2[64];
    __shared__ float s_ob1[64], s_og1[64], s_obt1[64], s_ob2[64];

    const int tid = threadIdx.x;
    for (int t = tid; t < 3 * 64;  t += MLP_BLOCK) s_ew1r[t] = ew1[32 * 64 + t];
    for (int t = tid; t < 64 * 64; t += MLP_BLOCK) s_ew2[t]  = ew2[t];
    for (int t = tid; t < 160 * 64; t += MLP_BLOCK) s_ow1[t] = ow1[t];
    for (int t = tid; t < 64 * 64; t += MLP_BLOCK) s_ow2[t]  = ow2[t];
    if (tid < 64) {
        s_eg1[tid] = eg1[tid];  s_ebt1[tid] = ebt1[tid]; s_eb2[tid] = eb2[tid];
        s_ob1[tid] = ob1[tid];  s_og1[tid] = og1[tid];
        s_obt1[tid] = obt1[tid]; s_ob2[tid] = ob2[tid];
    }
    __syncthreads();

    const int lane = tid & 63;
    const int wave = tid >> 6;
    const int c    = lane;
    const int grp  = blockIdx.x * WPB + wave;
    const int m0   = __builtin_amdgcn_readfirstlane(grp * MT);

    const float Ws0 = cst[0], Ws1 = cst[1], Ws2 = cst[2];
    const float Gxx = cst[3], Gyy = cst[4], Gzz = cst[5];
    const float Gxy = cst[6], Gxz = cst[7], Gyz = cst[8];

    const float inv64 = 1.0f / 64.0f;

    // ---- LN-stat setup: lane l owns combo (pp = l>>4, jq = l&15) ----
    const int pp = lane >> 4, jq = lane & 15;
    const int nl = knn_idx[(m0 + pp) * KNN + jq];
    float S1  = aux[nl * 8 + 0], Q = aux[nl * 8 + 1];
    float P1x = aux[nl * 8 + 2], P1y = aux[nl * 8 + 3], P1z = aux[nl * 8 + 4];
    float rxl = verts[nl * 3 + 0] - grid_verts[(m0 + pp) * 3 + 0];
    float ryl = verts[nl * 3 + 1] - grid_verts[(m0 + pp) * 3 + 1];
    float rzl = verts[nl * 3 + 2] - grid_verts[(m0 + pp) * 3 + 2];
    float s1l = S1 + rxl * Ws0 + ryl * Ws1 + rzl * Ws2;
    float s2l = Q + 2.0f * (rxl * P1x + ryl * P1y + rzl * P1z)
              + rxl * rxl * Gxx + ryl * ryl * Gyy + rzl * rzl * Gzz
              + 2.0f * (rxl * ryl * Gxy + rxl * rzl * Gxz + ryl * rzl * Gyz);
    float meanl  = s1l * inv64;
    float varl   = s2l * inv64 - meanl * meanl;
    float irstdl = rsqrtf(varl + 1e-5f);

    float gsum[MT];
#pragma unroll
    for (int p = 0; p < MT; ++p) gsum[p] = 0.0f;

#pragma unroll
    for (int p = 0; p < MT; ++p) {
#pragma unroll
        for (int j = 0; j < KNN; ++j) {
            const int src = p * 16 + j;   // compile-time readlane index
            int n = __builtin_amdgcn_readfirstlane(knn_idx[(m0 + p) * KNN + j]);
            float hv = pre[(size_t)n * COUT + c];
            float rx = lane_bcast(rxl, src);
            float ry = lane_bcast(ryl, src);
            float rz = lane_bcast(rzl, src);
            hv = fmaf(rx, s_ew1r[0 * 64 + c], hv);
            hv = fmaf(ry, s_ew1r[1 * 64 + c], hv);
            hv = fmaf(rz, s_ew1r[2 * 64 + c], hv);
            float mean  = lane_bcast(meanl, src);
            float irstd = lane_bcast(irstdl, src);
            float xn = (hv - mean) * irstd;
            gsum[p] += gelu_fast(xn * s_eg1[c] + s_ebt1[c]);
        }
    }

    float A[MT];
#pragma unroll
    for (int p = 0; p < MT; ++p) { gsum[p] *= (1.0f / 16.0f); A[p] = s_eb2[c]; }
    for (int jj = 0; jj < 64; ++jj) {
        float w = s_ew2[jj * 64 + c];
#pragma unroll
        for (int p = 0; p < MT; ++p)
            A[p] = fmaf(lane_bcast(gsum[p], jj), w, A[p]);
    }

    float gfa[MT], gfb[MT];
#pragma unroll
    for (int p = 0; p < MT; ++p) {
        gfa[p] = grid_feat[(size_t)(m0 + p) * CPROV + c];
        gfb[p] = grid_feat[(size_t)(m0 + p) * CPROV + 64 + (c & 31)];
    }
    float t1[MT];
#pragma unroll
    for (int p = 0; p < MT; ++p) t1[p] = s_ob1[c];
    for (int jj = 0; jj < 64; ++jj) {
        float w = s_ow1[jj * 64 + c];
#pragma unroll
        for (int p = 0; p < MT; ++p)
            t1[p] = fmaf(lane_bcast(A[p], jj), w, t1[p]);
    }
    for (int i = 0; i < 64; ++i) {
        float w = s_ow1[(64 + i) * 64 + c];
#pragma unroll
        for (int p = 0; p < MT; ++p)
            t1[p] = fmaf(lane_bcast(gfa[p], i), w, t1[p]);
    }
    for (int i = 0; i < 32; ++i) {
        float w = s_ow1[(128 + i) * 64 + c];
#pragma unroll
        for (int p = 0; p < MT; ++p)
            t1[p] = fmaf(lane_bcast(gfb[p], i), w, t1[p]);
    }

#pragma unroll
    for (int p = 0; p < MT; ++p) {
        float x = t1[p];
        float s = x, s2 = x * x;
#pragma unroll
        for (int off = 32; off; off >>= 1) {
            s  += __shfl_xor(s, off);
            s2 += __shfl_xor(s2, off);
        }
        float mean = s * inv64;
        float var  = s2 * inv64 - mean * mean;
        float xn = (x - mean) * rsqrtf(var + 1e-5f);
        t1[p] = gelu_fast(xn * s_og1[c] + s_obt1[c]);
    }

    float o[MT];
#pragma unroll
    for (int p = 0; p < MT; ++p) o[p] = s_ob2[c];
    for (int jj = 0; jj < 64; ++jj) {
        float w = s_ow2[jj * 64 + c];
#pragma unroll
        for (int p = 0; p < MT; ++p)
            o[p] = fmaf(lane_bcast(t1[p], jj), w, o[p]);
    }
#pragma unroll
    for (int p = 0; p < MT; ++p)
        out[(size_t)(m0 + p) * COUT + c] = o[p];
}

// ---------------------------------------------------------------------------
extern "C" void kernel_launch(void* const* d_in, const int* in_sizes, int n_in,
                              void* d_out, int out_size, void* d_ws, size_t ws_size,
                              hipStream_t stream)
{
    const float* verts  = (const float*)d_in[0];
    const float* feats  = (const float*)d_in[1];
    const float* gverts = (const float*)d_in[2];
    const float* gfeat  = (const float*)d_in[3];
    const float* ew1    = (const float*)d_in[4];
    const float* eb1    = (const float*)d_in[5];
    const float* eg1    = (const float*)d_in[6];
    const float* ebt1   = (const float*)d_in[7];
    const float* ew2    = (const float*)d_in[8];
    const float* eb2    = (const float*)d_in[9];
    const float* ow1    = (const float*)d_in[10];
    const float* ob1    = (const float*)d_in[11];
    const float* og1    = (const float*)d_in[12];
    const float* obt1   = (const float*)d_in[13];
    const float* ow2    = (const float*)d_in[14];
    const float* ob2    = (const float*)d_in[15];
    float* out = (float*)d_out;

    char* ws = (char*)d_ws;
    int*    counts  = (int*)(ws + 0);              // 128 KB
    int*    cursor  = (int*)(ws + 131072);         // 128 KB (memset with counts)
    int*    prefix  = (int*)(ws + 262144);         // 32769 ints -> ends 393220
    float*  tau     = (float*)(ws + 393224);       // 128 KB -> ends 524296
    int*    knn_idx = (int*)(ws + 524296);         // 2 MB -> ends 2621448
    float4* vps     = (float4*)(ws + 2621456);     // 128 KB (16-aligned) -> 2752528
    int*    vidx    = (int*)(ws + 2752528);        // 32 KB -> ends 2785296
    float*  pre     = (float*)(ws + 2785296);      // 2 MB -> ends 4882448
    float*  aux     = (float*)(ws + 4882448);      // 256 KB -> ends 5144592
    float*  cst     = (float*)(ws + 5144592);      // 64 B

    hipMemsetAsync(counts, 0, 262144, stream);     // counts + cursor
    bin_count_kernel<<<NV / 256, 256, 0, stream>>>(verts, counts);
    prefix_kernel<<<1, 1024, 0, stream>>>(counts, prefix);
    radius_kernel<<<NM / 256, 256, 0, stream>>>(gverts, prefix, tau);
    scatter_kernel<<<NV / 256, 256, 0, stream>>>(verts, prefix, cursor, vps, vidx);
    knn_spatial_kernel<<<NM / 64, 1024, 0, stream>>>(vps, vidx, prefix, gverts, tau, knn_idx);
    pre_edge_kernel<<<(NV * COUT) / 256, 256, 0, stream>>>(feats, ew1, eb1, pre, aux);
    const_kernel<<<1, 64, 0, stream>>>(ew1, cst);
    mlp_kernel<<<NM / (MT * WPB), MLP_BLOCK, 0, stream>>>(verts, gverts, gfeat,
        pre, aux, cst, knn_idx,
        ew1, eg1, ebt1, ew2, eb2, ow1, ob1, og1, obt1, ow2, ob2, out);
}

// Round 8
// 266.583 us; speedup vs baseline: 12.3561x; 1.0742x over previous
//
#include <hip/hip_runtime.h>
#include <cfloat>
#include <cstdint>
#include <cmath>

#define NV    8192
#define NM    32768
#define KNN   16
#define CIN   32
#define COUT  64
#define CPROV 96
#define CAPB  8      // FIFO depth per lane
#define MT    4      // grid points per wave in mlp kernel (validated R6/R7)
#define MLP_BLOCK 1024
#define WPB   (MLP_BLOCK/64)

// ===========================================================================
// KNN v3.2. R7 post-mortem: drains dominated (per-column drains run
// wave-max(cnt) iterations of 96-VALU key_insert; sum of per-column maxima
// ~90 iters/wave ~ 8.6k VALU >> 600 VALU of d2 work). This round:
//   - drains are RARE: only when __any(cnt >= 5) after a column, plus one
//     final drain; FIFO-overflow fallback (direct key_insert) keeps
//     correctness if a burst fills the FIFO between checks.
//   - drains are FIXED-COST: pad FIFO to 8 with ~0ULL, Batcher sort-8
//     (19 comparators), then the SAME validated bitonic 16+8 min-merge
//     (a[8+j] = min(a[8+j], f[7-j]) is the cross-wave merge identity with
//     the upper 8 of b = +INF) + 4-stage clean. ~360 VALU per drain vs
//     mx*96. Set-of-keys semantics identical => bit-identical output.
// Gate semantics unchanged: gd always equals a[15]'s d2 (monotone).
// ===========================================================================

__device__ __forceinline__ unsigned long long d2key(float d2, unsigned int idx) {
    unsigned int b = __float_as_uint(d2);
    b ^= (b & 0x80000000u) ? 0xFFFFFFFFu : 0x80000000u;  // total-order map
    return ((unsigned long long)b << 32) | idx;
}

__device__ __forceinline__ float key_d2f(unsigned long long key) {
    unsigned int b = (unsigned int)(key >> 32);
    b = (b & 0x80000000u) ? (b ^ 0x80000000u) : ~b;      // inverse map
    return __uint_as_float(b);
}

__device__ __forceinline__ void key_insert(unsigned long long* a,
                                           unsigned long long key) {
    // branchless sorted (ascending) insert-and-drop-max
#pragma unroll
    for (int i = KNN - 1; i >= 1; --i) {
        unsigned long long hi = (a[i-1] > key) ? a[i-1] : key;
        a[i] = (hi < a[i]) ? hi : a[i];
    }
    a[0] = (key < a[0]) ? key : a[0];
}

__device__ __forceinline__ int bin_of(float x) {
    int b = (int)(x * 32.0f);
    return min(31, max(0, b));
}

__global__ __launch_bounds__(256) void bin_count_kernel(
    const float* __restrict__ verts, int* __restrict__ counts)
{
    int v = blockIdx.x * 256 + threadIdx.x;
    int bx = bin_of(verts[v * 3 + 0]);
    int by = bin_of(verts[v * 3 + 1]);
    int bz = bin_of(verts[v * 3 + 2]);
    atomicAdd(&counts[(bx * 32 + by) * 32 + bz], 1);
}

__global__ __launch_bounds__(1024) void prefix_kernel(
    const int* __restrict__ counts, int* __restrict__ prefix)
{
    __shared__ int lds[1024];
    int tid = threadIdx.x;
    int local[32]; int s = 0;
#pragma unroll
    for (int i = 0; i < 32; ++i) { local[i] = counts[tid * 32 + i]; s += local[i]; }
    lds[tid] = s; __syncthreads();
    for (int off = 1; off < 1024; off <<= 1) {
        int v = (tid >= off) ? lds[tid - off] : 0;
        __syncthreads();
        lds[tid] += v;
        __syncthreads();
    }
    int run = lds[tid] - s;
#pragma unroll
    for (int i = 0; i < 32; ++i) { prefix[tid * 32 + i] = run; run += local[i]; }
    if (tid == 1023) prefix[32768] = run;
}

// tau[m] = 3*(R+1)^2 where radius-R cell cube holds >= 16 points (validated)
__global__ __launch_bounds__(256) void radius_kernel(
    const float* __restrict__ grid_verts, const int* __restrict__ prefix,
    float* __restrict__ tau)
{
    int m = blockIdx.x * 256 + threadIdx.x;
    int bx = bin_of(grid_verts[m * 3 + 0]);
    int by = bin_of(grid_verts[m * 3 + 1]);
    int bz = bin_of(grid_verts[m * 3 + 2]);
    int R = 1;
    for (; R < 32; ++R) {
        int cnt = 0;
        int xlo = max(0, bx - R), xhi = min(31, bx + R);
        int ylo = max(0, by - R), yhi = min(31, by + R);
        int zlo = max(0, bz - R), zhi = min(31, bz + R);
        for (int x = xlo; x <= xhi; ++x)
            for (int y = ylo; y <= yhi; ++y) {
                int c = (x * 32 + y) * 32;
                cnt += prefix[c + zhi + 1] - prefix[c + zlo];
            }
        if (cnt >= KNN) break;
    }
    float Rp = (float)(R + 1);
    tau[m] = 3.0f * Rp * Rp;
}

// scatter points into bin order; pack (r0,r1,r2,rr) with the EXACT rounding
// sequence of the validated path.
__global__ __launch_bounds__(256) void scatter_kernel(
    const float* __restrict__ verts, const int* __restrict__ prefix,
    int* __restrict__ cursor, float4* __restrict__ vps, int* __restrict__ vidx)
{
    int v = blockIdx.x * 256 + threadIdx.x;
    float x0 = verts[v * 3 + 0], x1 = verts[v * 3 + 1], x2 = verts[v * 3 + 2];
    float r0 = __fmul_rn(x0, 32.0f);
    float r1 = __fmul_rn(x1, 32.0f);
    float r2 = __fmul_rn(x2, 32.0f);
    float rr = __fadd_rn(__fadd_rn(__fmul_rn(r0, r0), __fmul_rn(r1, r1)),
                         __fmul_rn(r2, r2));
    int bx = min(31, max(0, (int)r0));
    int by = min(31, max(0, (int)r1));
    int bz = min(31, max(0, (int)r2));
    int b = (bx * 32 + by) * 32 + bz;
    int pos = prefix[b] + atomicAdd(&cursor[b], 1);
    vps[pos] = make_float4(r0, r1, r2, rr);
    vidx[pos] = v;
}

#define CSWAP(i, j) { unsigned long long x_ = a[i], y_ = a[j]; \
                      bool c_ = x_ < y_; \
                      a[i] = c_ ? x_ : y_; a[j] = c_ ? y_ : x_; }
#define FSWAP(i, j) { unsigned long long x_ = f[i], y_ = f[j]; \
                      bool c_ = x_ < y_; \
                      f[i] = c_ ? x_ : y_; f[j] = c_ ? y_ : x_; }

// clean bitonic-16 -> ascending (4 half-clean stages; validated idiom)
#define CLEAN16 \
    CSWAP(0, 8)  CSWAP(1, 9)  CSWAP(2, 10) CSWAP(3, 11) \
    CSWAP(4, 12) CSWAP(5, 13) CSWAP(6, 14) CSWAP(7, 15) \
    CSWAP(0, 4)  CSWAP(1, 5)  CSWAP(2, 6)  CSWAP(3, 7)  \
    CSWAP(8, 12) CSWAP(9, 13) CSWAP(10, 14) CSWAP(11, 15)\
    CSWAP(0, 2)  CSWAP(1, 3)  CSWAP(4, 6)  CSWAP(5, 7)  \
    CSWAP(8, 10) CSWAP(9, 11) CSWAP(12, 14) CSWAP(13, 15)\
    CSWAP(0, 1)  CSWAP(2, 3)  CSWAP(4, 5)  CSWAP(6, 7)  \
    CSWAP(8, 9)  CSWAP(10, 11) CSWAP(12, 13) CSWAP(14, 15)

__global__ __launch_bounds__(1024, 4) void knn_spatial_kernel(
    const float4* __restrict__ vps,
    const int*    __restrict__ vidx,
    const int*    __restrict__ prefix,
    const float*  __restrict__ grid_verts,
    const float*  __restrict__ tau,
    int* __restrict__ knn_idx)
{
    __shared__ unsigned long long buf[8192];   // 64 KB: scan FIFO, then merge slots
    const int tid  = threadIdx.x;
    const int lane = tid & 63;
    const int w    = tid >> 6;                 // wave id

    // brick decomposition: 8x8x8 bricks of 4x4x4 grid cells; lane -> local cell
    const int bx4 = (blockIdx.x >> 6) * 4;
    const int by4 = ((blockIdx.x >> 3) & 7) * 4;
    const int bz4 = (blockIdx.x & 7) * 4;
    const int lx = lane >> 4, ly = (lane >> 2) & 3, lz = lane & 3;
    const int m = ((bx4 + lx) * 32 + (by4 + ly)) * 32 + (bz4 + lz);

    const float q0 = __fmul_rn(grid_verts[m * 3 + 0], 32.0f);
    const float q1 = __fmul_rn(grid_verts[m * 3 + 1], 32.0f);
    const float q2 = __fmul_rn(grid_verts[m * 3 + 2], 32.0f);
    const float qq = __fadd_rn(__fadd_rn(__fmul_rn(q0, q0), __fmul_rn(q1, q1)),
                               __fmul_rn(q2, q2));

    const float tm = tau[m];
    // seed = key(bound), idx 0; bound > all golden top-16 d2 (validated margin)
    const float bound = tm + 0.13f;
    unsigned int bb = __float_as_uint(bound) ^ 0x80000000u;  // bound > 0
    const unsigned long long seed = ((unsigned long long)bb << 32);

    unsigned long long a[KNN];
#pragma unroll
    for (int s = 0; s < KNN; ++s) a[s] = seed;
    float gd = bound;      // d2-domain gate = d2 part of a[15]
    int cnt = 0;

    // block-uniform tau max (identical in every wave: lane->query map is
    // wave-independent)
    float tmax = tm;
#pragma unroll
    for (int off = 32; off; off >>= 1)
        tmax = fmaxf(tmax, __uint_as_float(__shfl_xor(__float_as_uint(tmax), off)));

    int rs = (int)sqrtf(tmax) + 1;
    rs = min(31, max(1, rs));                  // poison-bounded
    const int xlo = max(0, bx4 - rs), xhi = min(31, bx4 + 3 + rs);
    const int ylo = max(0, by4 - rs), yhi = min(31, by4 + 3 + rs);
    const int ny = yhi - ylo + 1;
    const int npair = (xhi - xlo + 1) * ny;

    int xx = xlo + w / ny;                     // w < 16, ny >= 8 on clean data
    int yy = ylo + w % ny;
    for (int pi = w; pi < npair; pi += 16) {
        // per-column distance budget (sphere clip); all-int fp32 => exact
        int cdx = max(0, max(bx4 - xx, xx - bx4 - 3));
        int cdy = max(0, max(by4 - yy, yy - by4 - 3));
        int mdx = max(0, cdx - 1), mdy = max(0, cdy - 1);
        float rem = tmax - (float)(mdx * mdx + mdy * mdy);
        if (rem >= 0.0f) {
            int zrc = (int)sqrtf(rem) + 1;
            zrc = min(31, max(0, zrc));        // poison-bounded
            const int zl = max(0, bz4 - zrc), zh = min(31, bz4 + 3 + zrc);
            const int cxx = min(xx, 31);       // poison-bounded
            const int c = (cxx * 32 + yy) * 32;
            int pstart = prefix[c + zl];
            int pend   = prefix[c + zh + 1];
            pstart = min(max(pstart, 0), NV);  // poison-bounded
            pend   = min(max(pend, pstart), NV);
#pragma unroll 2
            for (int p = pstart; p < pend; ++p) {
                float4 v = vps[p];
                float dot = fmaf(q2, v.z, fmaf(q1, v.y, __fmul_rn(q0, v.x)));
                // == (qq+rr) - 2*dot bit-exactly (2*dot exact)
                float d2 = fmaf(-2.0f, dot, __fadd_rn(qq, v.w));
                if (d2 <= gd) {     // conservative: ties resolved by insert
                    unsigned long long key = d2key(d2, (unsigned int)vidx[p]);
                    if (cnt < CAPB) { buf[cnt * 1024 + tid] = key; ++cnt; }
                    else {  // burst overflow: exact direct insert, tighten gate
                        key_insert(a, key);
                        gd = key_d2f(a[KNN - 1]);
                    }
                }
            }
            // deferred fixed-cost drain: only when some lane is near-full
            if (__any(cnt >= 5)) {
                unsigned long long f[CAPB];
#pragma unroll
                for (int k = 0; k < CAPB; ++k)
                    f[k] = (k < cnt) ? buf[k * 1024 + tid] : ~0ULL;
                // Batcher odd-even mergesort, 8 elements, 19 comparators
                FSWAP(0,1) FSWAP(2,3) FSWAP(4,5) FSWAP(6,7)
                FSWAP(0,2) FSWAP(1,3) FSWAP(4,6) FSWAP(5,7)
                FSWAP(1,2) FSWAP(5,6)
                FSWAP(0,4) FSWAP(1,5) FSWAP(2,6) FSWAP(3,7)
                FSWAP(2,4) FSWAP(3,5)
                FSWAP(1,2) FSWAP(3,4) FSWAP(5,6)
                // bitonic 16+8 min-merge (upper 8 of b = +INF) + clean
#pragma unroll
                for (int j = 0; j < 8; ++j) {
                    unsigned long long b = f[7 - j];
                    if (b < a[8 + j]) a[8 + j] = b;
                }
                CLEAN16
                gd = key_d2f(a[KNN - 1]);
                cnt = 0;
            }
        }
        // advance (xx,yy) by 16 columns; ny >= 8 => at most 2 carries
        yy += 16;
        if (yy > yhi) { yy -= ny; ++xx; }
        if (yy > yhi) { yy -= ny; ++xx; }
    }

    // final drain (FIFO may hold keys)
    if (__any(cnt > 0)) {
        unsigned long long f[CAPB];
#pragma unroll
        for (int k = 0; k < CAPB; ++k)
            f[k] = (k < cnt) ? buf[k * 1024 + tid] : ~0ULL;
        FSWAP(0,1) FSWAP(2,3) FSWAP(4,5) FSWAP(6,7)
        FSWAP(0,2) FSWAP(1,3) FSWAP(4,6) FSWAP(5,7)
        FSWAP(1,2) FSWAP(5,6)
        FSWAP(0,4) FSWAP(1,5) FSWAP(2,6) FSWAP(3,7)
        FSWAP(2,4) FSWAP(3,5)
        FSWAP(1,2) FSWAP(3,4) FSWAP(5,6)
#pragma unroll
        for (int j = 0; j < 8; ++j) {
            unsigned long long b = f[7 - j];
            if (b < a[8 + j]) a[8 + j] = b;
        }
        CLEAN16
    }

    // ---- cross-wave merge tree: 16 sorted lists -> 1, bitonic in registers ----
    // round half: waves [half,2*half) publish, waves [0,half) merge slot w.
    for (int half = 8; half >= 1; half >>= 1) {
        __syncthreads();                       // prior reads done before overwrite
        if (w >= half && w < 2 * half) {
            unsigned long long* dst = &buf[(w - half) * 1024];
#pragma unroll
            for (int s = 0; s < KNN; ++s) dst[s * 64 + lane] = a[s];
        }
        __syncthreads();
        if (w < half) {
            const unsigned long long* src = &buf[w * 1024];
            // L[i] = min(a[i], b[15-i]) : 16 smallest of union, bitonic
#pragma unroll
            for (int i = 0; i < KNN; ++i) {
                unsigned long long b = src[(KNN - 1 - i) * 64 + lane];
                a[i] = (b < a[i]) ? b : a[i];
            }
            CLEAN16
        }
    }

    if (w == 0) {
#pragma unroll
        for (int s = 0; s < KNN; ++s)
            knn_idx[m * KNN + s] = (int)(a[s] & 0xFFFFFFFFu);
    }
}

// ===========================================================================
// MLP precompute (unchanged — passed)
// ===========================================================================

__global__ void const_kernel(const float* __restrict__ ew1, float* __restrict__ cst)
{
    int c = threadIdx.x;   // 64 threads
    float w0 = ew1[32 * 64 + c], w1 = ew1[33 * 64 + c], w2 = ew1[34 * 64 + c];
    float v[9] = { w0, w1, w2, w0*w0, w1*w1, w2*w2, w0*w1, w0*w2, w1*w2 };
#pragma unroll
    for (int k = 0; k < 9; ++k) {
#pragma unroll
        for (int off = 32; off; off >>= 1) v[k] += __shfl_xor(v[k], off);
    }
    if (c == 0) {
        cst[0] = v[0]; cst[1] = v[1]; cst[2] = v[2];
        cst[3] = v[3]; cst[4] = v[4]; cst[5] = v[5];
        cst[6] = v[6]; cst[7] = v[7]; cst[8] = v[8];
    }
}

__global__ __launch_bounds__(256) void pre_edge_kernel(
    const float* __restrict__ feats, const float* __restrict__ ew1,
    const float* __restrict__ eb1, float* __restrict__ pre,
    float* __restrict__ aux)
{
    int t = blockIdx.x * 256 + threadIdx.x;
    int n = t >> 6, c = t & 63;
    float acc = eb1[c];
#pragma unroll
    for (int i = 0; i < CIN; ++i)
        acc = fmaf(feats[n * CIN + i], ew1[i * COUT + c], acc);
    pre[t] = acc;

    float w0 = ew1[32 * 64 + c], w1 = ew1[33 * 64 + c], w2 = ew1[34 * 64 + c];
    float v[5] = { acc, acc * acc, acc * w0, acc * w1, acc * w2 };
#pragma unroll
    for (int k = 0; k < 5; ++k) {
#pragma unroll
        for (int off = 32; off; off >>= 1) v[k] += __shfl_xor(v[k], off);
    }
    if (c == 0) {
        aux[n * 8 + 0] = v[0]; aux[n * 8 + 1] = v[1];
        aux[n * 8 + 2] = v[2]; aux[n * 8 + 3] = v[3]; aux[n * 8 + 4] = v[4];
    }
}

// ===========================================================================
// Main MLP (unchanged from R7 — passed; LN stats deduplicated via readlane)
// ===========================================================================
__device__ __forceinline__ float gelu_fast(float x) {
    float t = fmaf(0.044715f, x * x, 1.0f);
    float u = 0.7978845608028654f * x * t;
    float e = __expf(-2.0f * u);
    return x * __builtin_amdgcn_rcpf(1.0f + e);
}

__device__ __forceinline__ float lane_bcast(float v, int lane) {
    return __uint_as_float(__builtin_amdgcn_readlane(__float_as_uint(v), lane));
}

__global__ __launch_bounds__(MLP_BLOCK) void mlp_kernel(
    const float* __restrict__ verts,
    const float* __restrict__ grid_verts,
    const float* __restrict__ grid_feat,
    const float* __restrict__ pre,
    const float* __restrict__ aux,
    const float* __restrict__ cst,
    const int*   __restrict__ knn_idx,
    const float* __restrict__ ew1,
    const float* __restrict__ eg1, const float* __restrict__ ebt1,
    const float* __restrict__ ew2, const float* __restrict__ eb2,
    const float* __restrict__ ow1, const float* __restrict__ ob1,
    const float* __restrict__ og1, const float* __restrict__ obt1,
    const float* __restrict__ ow2, const float* __restrict__ ob2,
    float* __restrict__ out)
{
    __shared__ float s_ew1r[3 * 64];
    __shared__ float s_ew2[64 * 64];
    __shared__ float s_ow1[160 * 64];
    __shared__ float s_ow2[64 * 64];
    __shared__ float s_eg1[64], s_ebt1[64], s_eb2[64];
    __shared__ float s_ob1[64], s_og1[64], s_obt1[64], s_ob2[64];

    const int tid = threadIdx.x;
    for (int t = tid; t < 3 * 64;  t += MLP_BLOCK) s_ew1r[t] = ew1[32 * 64 + t];
    for (int t = tid; t < 64 * 64; t += MLP_BLOCK) s_ew2[t]  = ew2[t];
    for (int t = tid; t < 160 * 64; t += MLP_BLOCK) s_ow1[t] = ow1[t];
    for (int t = tid; t < 64 * 64; t += MLP_BLOCK) s_ow2[t]  = ow2[t];
    if (tid < 64) {
        s_eg1[tid] = eg1[tid];  s_ebt1[tid] = ebt1[tid]; s_eb2[tid] = eb2[tid];
        s_ob1[tid] = ob1[tid];  s_og1[tid] = og1[tid];
        s_obt1[tid] = obt1[tid]; s_ob2[tid] = ob2[tid];
    }
    __syncthreads();

    const int lane = tid & 63;
    const int wave = tid >> 6;
    const int c    = lane;
    const int grp  = blockIdx.x * WPB + wave;
    const int m0   = __builtin_amdgcn_readfirstlane(grp * MT);

    const float Ws0 = cst[0], Ws1 = cst[1], Ws2 = cst[2];
    const float Gxx = cst[3], Gyy = cst[4], Gzz = cst[5];
    const float Gxy = cst[6], Gxz = cst[7], Gyz = cst[8];

    const float inv64 = 1.0f / 64.0f;

    // ---- LN-stat setup: lane l owns combo (pp = l>>4, jq = l&15) ----
    const int pp = lane >> 4, jq = lane & 15;
    const int nl = knn_idx[(m0 + pp) * KNN + jq];
    float S1  = aux[nl * 8 + 0], Q = aux[nl * 8 + 1];
    float P1x = aux[nl * 8 + 2], P1y = aux[nl * 8 + 3], P1z = aux[nl * 8 + 4];
    float rxl = verts[nl * 3 + 0] - grid_verts[(m0 + pp) * 3 + 0];
    float ryl = verts[nl * 3 + 1] - grid_verts[(m0 + pp) * 3 + 1];
    float rzl = verts[nl * 3 + 2] - grid_verts[(m0 + pp) * 3 + 2];
    float s1l = S1 + rxl * Ws0 + ryl * Ws1 + rzl * Ws2;
    float s2l = Q + 2.0f * (rxl * P1x + ryl * P1y + rzl * P1z)
              + rxl * rxl * Gxx + ryl * ryl * Gyy + rzl * rzl * Gzz
              + 2.0f * (rxl * ryl * Gxy + rxl * rzl * Gxz + ryl * rzl * Gyz);
    float meanl  = s1l * inv64;
    float varl   = s2l * inv64 - meanl * meanl;
    float irstdl = rsqrtf(varl + 1e-5f);

    float gsum[MT];
#pragma unroll
    for (int p = 0; p < MT; ++p) gsum[p] = 0.0f;

#pragma unroll
    for (int p = 0; p < MT; ++p) {
#pragma unroll
        for (int j = 0; j < KNN; ++j) {
            const int src = p * 16 + j;   // compile-time readlane index
            int n = __builtin_amdgcn_readfirstlane(knn_idx[(m0 + p) * KNN + j]);
            float hv = pre[(size_t)n * COUT + c];
            float rx = lane_bcast(rxl, src);
            float ry = lane_bcast(ryl, src);
            float rz = lane_bcast(rzl, src);
            hv = fmaf(rx, s_ew1r[0 * 64 + c], hv);
            hv = fmaf(ry, s_ew1r[1 * 64 + c], hv);
            hv = fmaf(rz, s_ew1r[2 * 64 + c], hv);
            float mean  = lane_bcast(meanl, src);
            float irstd = lane_bcast(irstdl, src);
            float xn = (hv - mean) * irstd;
            gsum[p] += gelu_fast(xn * s_eg1[c] + s_ebt1[c]);
        }
    }

    float A[MT];
#pragma unroll
    for (int p = 0; p < MT; ++p) { gsum[p] *= (1.0f / 16.0f); A[p] = s_eb2[c]; }
    for (int jj = 0; jj < 64; ++jj) {
        float w = s_ew2[jj * 64 + c];
#pragma unroll
        for (int p = 0; p < MT; ++p)
            A[p] = fmaf(lane_bcast(gsum[p], jj), w, A[p]);
    }

    float gfa[MT], gfb[MT];
#pragma unroll
    for (int p = 0; p < MT; ++p) {
        gfa[p] = grid_feat[(size_t)(m0 + p) * CPROV + c];
        gfb[p] = grid_feat[(size_t)(m0 + p) * CPROV + 64 + (c & 31)];
    }
    float t1[MT];
#pragma unroll
    for (int p = 0; p < MT; ++p) t1[p] = s_ob1[c];
    for (int jj = 0; jj < 64; ++jj) {
        float w = s_ow1[jj * 64 + c];
#pragma unroll
        for (int p = 0; p < MT; ++p)
            t1[p] = fmaf(lane_bcast(A[p], jj), w, t1[p]);
    }
    for (int i = 0; i < 64; ++i) {
        float w = s_ow1[(64 + i) * 64 + c];
#pragma unroll
        for (int p = 0; p < MT; ++p)
            t1[p] = fmaf(lane_bcast(gfa[p], i), w, t1[p]);
    }
    for (int i = 0; i < 32; ++i) {
        float w = s_ow1[(128 + i) * 64 + c];
#pragma unroll
        for (int p = 0; p < MT; ++p)
            t1[p] = fmaf(lane_bcast(gfb[p], i), w, t1[p]);
    }

#pragma unroll
    for (int p = 0; p < MT; ++p) {
        float x = t1[p];
        float s = x, s2 = x * x;
#pragma unroll
        for (int off = 32; off; off >>= 1) {
            s  += __shfl_xor(s, off);
            s2 += __shfl_xor(s2, off);
        }
        float mean = s * inv64;
        float var  = s2 * inv64 - mean * mean;
        float xn = (x - mean) * rsqrtf(var + 1e-5f);
        t1[p] = gelu_fast(xn * s_og1[c] + s_obt1[c]);
    }

    float o[MT];
#pragma unroll
    for (int p = 0; p < MT; ++p) o[p] = s_ob2[c];
    for (int jj = 0; jj < 64; ++jj) {
        float w = s_ow2[jj * 64 + c];
#pragma unroll
        for (int p = 0; p < MT; ++p)
            o[p] = fmaf(lane_bcast(t1[p], jj), w, o[p]);
    }
#pragma unroll
    for (int p = 0; p < MT; ++p)
        out[(size_t)(m0 + p) * COUT + c] = o[p];
}

// ---------------------------------------------------------------------------
extern "C" void kernel_launch(void* const* d_in, const int* in_sizes, int n_in,
                              void* d_out, int out_size, void* d_ws, size_t ws_size,
                              hipStream_t stream)
{
    const float* verts  = (const float*)d_in[0];
    const float* feats  = (const float*)d_in[1];
    const float* gverts = (const float*)d_in[2];
    const float* gfeat  = (const float*)d_in[3];
    const float* ew1    = (const float*)d_in[4];
    const float* eb1    = (const float*)d_in[5];
    const float* eg1    = (const float*)d_in[6];
    const float* ebt1   = (const float*)d_in[7];
    const float* ew2    = (const float*)d_in[8];
    const float* eb2    = (const float*)d_in[9];
    const float* ow1    = (const float*)d_in[10];
    const float* ob1    = (const float*)d_in[11];
    const float* og1    = (const float*)d_in[12];
    const float* obt1   = (const float*)d_in[13];
    const float* ow2    = (const float*)d_in[14];
    const float* ob2    = (const float*)d_in[15];
    float* out = (float*)d_out;

    char* ws = (char*)d_ws;
    int*    counts  = (int*)(ws + 0);              // 128 KB
    int*    cursor  = (int*)(ws + 131072);         // 128 KB (memset with counts)
    int*    prefix  = (int*)(ws + 262144);         // 32769 ints -> ends 393220
    float*  tau     = (float*)(ws + 393224);       // 128 KB -> ends 524296
    int*    knn_idx = (int*)(ws + 524296);         // 2 MB -> ends 2621448
    float4* vps     = (float4*)(ws + 2621456);     // 128 KB (16-aligned) -> 2752528
    int*    vidx    = (int*)(ws + 2752528);        // 32 KB -> ends 2785296
    float*  pre     = (float*)(ws + 2785296);      // 2 MB -> ends 4882448
    float*  aux     = (float*)(ws + 4882448);      // 256 KB -> ends 5144592
    float*  cst     = (float*)(ws + 5144592);      // 64 B

    hipMemsetAsync(counts, 0, 262144, stream);     // counts + cursor
    bin_count_kernel<<<NV / 256, 256, 0, stream>>>(verts, counts);
    prefix_kernel<<<1, 1024, 0, stream>>>(counts, prefix);
    radius_kernel<<<NM / 256, 256, 0, stream>>>(gverts, prefix, tau);
    scatter_kernel<<<NV / 256, 256, 0, stream>>>(verts, prefix, cursor, vps, vidx);
    knn_spatial_kernel<<<NM / 64, 1024, 0, stream>>>(vps, vidx, prefix, gverts, tau, knn_idx);
    pre_edge_kernel<<<(NV * COUT) / 256, 256, 0, stream>>>(feats, ew1, eb1, pre, aux);
    const_kernel<<<1, 64, 0, stream>>>(ew1, cst);
    mlp_kernel<<<NM / (MT * WPB), MLP_BLOCK, 0, stream>>>(verts, gverts, gfeat,
        pre, aux, cst, knn_idx,
        ew1, eg1, ebt1, ew2, eb2, ow1, ob1, og1, obt1, ow2, ob2, out);
}

// Round 12
// 263.507 us; speedup vs baseline: 12.5003x; 1.0117x over previous
//
#include <hip/hip_runtime.h>
#include <cfloat>
#include <cstdint>
#include <cmath>

#define NV    8192
#define NM    32768
#define KNN   16
#define CIN   32
#define COUT  64
#define CPROV 96
#define CAPB  8      // FIFO depth per lane
#define MT    4      // grid points per wave in mlp kernel (validated R6/R7)
#define MLP_BLOCK 1024
#define WPB   (MLP_BLOCK/64)

// ===========================================================================
// R9: attack the ~112 us of unprofiled small-kernel + launch-gap time
// (stable across R5-R8; knn 78.5 + mlp ~76 vs total 266.6).
//   - radius_kernel was 128 blocks = 2 waves/CU, each thread serially
//     issuing ~100 dependent L2 loads. Now ONE WAVE PER QUERY: 64 lanes
//     split the R-cube columns, integer partial sums, shfl reduce --
//     integer addition is exact & order-independent => identical R/tau.
//   - mega-kernel fusion of independent stages (branch on blockIdx):
//       A: pre_edge (2048 blk) || const (1 blk) || bin_count (32 blk)
//       B: radius_coop (8192 blk) || scatter (32 blk)
//     9 dispatches -> 6.
// knn_spatial (78.5 us) and mlp (~76 us) unchanged from R8 (both passed).
// ===========================================================================

__device__ __forceinline__ unsigned long long d2key(float d2, unsigned int idx) {
    unsigned int b = __float_as_uint(d2);
    b ^= (b & 0x80000000u) ? 0xFFFFFFFFu : 0x80000000u;  // total-order map
    return ((unsigned long long)b << 32) | idx;
}

__device__ __forceinline__ float key_d2f(unsigned long long key) {
    unsigned int b = (unsigned int)(key >> 32);
    b = (b & 0x80000000u) ? (b ^ 0x80000000u) : ~b;      // inverse map
    return __uint_as_float(b);
}

__device__ __forceinline__ void key_insert(unsigned long long* a,
                                           unsigned long long key) {
    // branchless sorted (ascending) insert-and-drop-max
#pragma unroll
    for (int i = KNN - 1; i >= 1; --i) {
        unsigned long long hi = (a[i-1] > key) ? a[i-1] : key;
        a[i] = (hi < a[i]) ? hi : a[i];
    }
    a[0] = (key < a[0]) ? key : a[0];
}

__device__ __forceinline__ int bin_of(float x) {
    int b = (int)(x * 32.0f);
    return min(31, max(0, b));
}

__global__ __launch_bounds__(1024) void prefix_kernel(
    const int* __restrict__ counts, int* __restrict__ prefix)
{
    __shared__ int lds[1024];
    int tid = threadIdx.x;
    int local[32]; int s = 0;
#pragma unroll
    for (int i = 0; i < 32; ++i) { local[i] = counts[tid * 32 + i]; s += local[i]; }
    lds[tid] = s; __syncthreads();
    for (int off = 1; off < 1024; off <<= 1) {
        int v = (tid >= off) ? lds[tid - off] : 0;
        __syncthreads();
        lds[tid] += v;
        __syncthreads();
    }
    int run = lds[tid] - s;
#pragma unroll
    for (int i = 0; i < 32; ++i) { prefix[tid * 32 + i] = run; run += local[i]; }
    if (tid == 1023) prefix[32768] = run;
}

// ---------------------------------------------------------------------------
// Fused stage A: pre_edge (blocks 0..2047) | const (2048) | bin_count (2049..)
// ---------------------------------------------------------------------------
__global__ __launch_bounds__(256) void fused_pre_kernel(
    const float* __restrict__ verts, const float* __restrict__ feats,
    const float* __restrict__ ew1, const float* __restrict__ eb1,
    int* __restrict__ counts, float* __restrict__ pre,
    float* __restrict__ aux, float* __restrict__ cst)
{
    const int bid = blockIdx.x;
    const int tid = threadIdx.x;
    if (bid < 2048) {
        // ---- pre_edge (validated) ----
        int t = bid * 256 + tid;
        int n = t >> 6, c = t & 63;
        float acc = eb1[c];
#pragma unroll
        for (int i = 0; i < CIN; ++i)
            acc = fmaf(feats[n * CIN + i], ew1[i * COUT + c], acc);
        pre[t] = acc;

        float w0 = ew1[32 * 64 + c], w1 = ew1[33 * 64 + c], w2 = ew1[34 * 64 + c];
        float v[5] = { acc, acc * acc, acc * w0, acc * w1, acc * w2 };
#pragma unroll
        for (int k = 0; k < 5; ++k) {
#pragma unroll
            for (int off = 32; off; off >>= 1) v[k] += __shfl_xor(v[k], off);
        }
        if (c == 0) {
            aux[n * 8 + 0] = v[0]; aux[n * 8 + 1] = v[1];
            aux[n * 8 + 2] = v[2]; aux[n * 8 + 3] = v[3]; aux[n * 8 + 4] = v[4];
        }
    } else if (bid == 2048) {
        // ---- const (validated) ----
        if (tid < 64) {
            int c = tid;
            float w0 = ew1[32 * 64 + c], w1 = ew1[33 * 64 + c], w2 = ew1[34 * 64 + c];
            float v[9] = { w0, w1, w2, w0*w0, w1*w1, w2*w2, w0*w1, w0*w2, w1*w2 };
#pragma unroll
            for (int k = 0; k < 9; ++k) {
#pragma unroll
                for (int off = 32; off; off >>= 1) v[k] += __shfl_xor(v[k], off);
            }
            if (c == 0) {
                cst[0] = v[0]; cst[1] = v[1]; cst[2] = v[2];
                cst[3] = v[3]; cst[4] = v[4]; cst[5] = v[5];
                cst[6] = v[6]; cst[7] = v[7]; cst[8] = v[8];
            }
        }
    } else {
        // ---- bin_count (validated) ----
        int v = (bid - 2049) * 256 + tid;
        int bx = bin_of(verts[v * 3 + 0]);
        int by = bin_of(verts[v * 3 + 1]);
        int bz = bin_of(verts[v * 3 + 2]);
        atomicAdd(&counts[(bx * 32 + by) * 32 + bz], 1);
    }
}

// ---------------------------------------------------------------------------
// Fused stage B: radius_coop (blocks 0..8191, one wave per query) |
//                scatter (blocks 8192..8223)
// ---------------------------------------------------------------------------
__global__ __launch_bounds__(256) void fused_grid_kernel(
    const float* __restrict__ verts, const float* __restrict__ grid_verts,
    const int* __restrict__ prefix, int* __restrict__ cursor,
    float* __restrict__ tau, float4* __restrict__ vps, int* __restrict__ vidx)
{
    const int bid = blockIdx.x;
    const int tid = threadIdx.x;
    if (bid < 8192) {
        // ---- radius, wave-cooperative: wave w owns query m ----
        const int lane = tid & 63;
        const int w    = tid >> 6;
        const int m    = bid * 4 + w;
        const int bx = bin_of(grid_verts[m * 3 + 0]);
        const int by = bin_of(grid_verts[m * 3 + 1]);
        const int bz = bin_of(grid_verts[m * 3 + 2]);
        int R = 1;
        for (; R < 32; ++R) {
            int xlo = max(0, bx - R), xhi = min(31, bx + R);
            int ylo = max(0, by - R), yhi = min(31, by + R);
            int zlo = max(0, bz - R), zhi = min(31, bz + R);
            int nyy = yhi - ylo + 1;
            int ncol = (xhi - xlo + 1) * nyy;
            int cnt = 0;
            for (int ci = lane; ci < ncol; ci += 64) {
                int x = xlo + ci / nyy, y = ylo + ci % nyy;
                int c = (x * 32 + y) * 32;
                cnt += prefix[c + zhi + 1] - prefix[c + zlo];
            }
            // integer reduce: exact, order-independent => same R as serial
#pragma unroll
            for (int off = 32; off; off >>= 1) cnt += __shfl_xor(cnt, off);
            if (cnt >= KNN) break;
        }
        if (lane == 0) {
            float Rp = (float)(R + 1);
            tau[m] = 3.0f * Rp * Rp;
        }
    } else {
        // ---- scatter (validated; EXACT pack rounding sequence) ----
        int v = (bid - 8192) * 256 + tid;
        float x0 = verts[v * 3 + 0], x1 = verts[v * 3 + 1], x2 = verts[v * 3 + 2];
        float r0 = __fmul_rn(x0, 32.0f);
        float r1 = __fmul_rn(x1, 32.0f);
        float r2 = __fmul_rn(x2, 32.0f);
        float rr = __fadd_rn(__fadd_rn(__fmul_rn(r0, r0), __fmul_rn(r1, r1)),
                             __fmul_rn(r2, r2));
        int bx = min(31, max(0, (int)r0));
        int by = min(31, max(0, (int)r1));
        int bz = min(31, max(0, (int)r2));
        int b = (bx * 32 + by) * 32 + bz;
        int pos = prefix[b] + atomicAdd(&cursor[b], 1);
        vps[pos] = make_float4(r0, r1, r2, rr);
        vidx[pos] = v;
    }
}

#define CSWAP(i, j) { unsigned long long x_ = a[i], y_ = a[j]; \
                      bool c_ = x_ < y_; \
                      a[i] = c_ ? x_ : y_; a[j] = c_ ? y_ : x_; }
#define FSWAP(i, j) { unsigned long long x_ = f[i], y_ = f[j]; \
                      bool c_ = x_ < y_; \
                      f[i] = c_ ? x_ : y_; f[j] = c_ ? y_ : x_; }

// clean bitonic-16 -> ascending (4 half-clean stages; validated idiom)
#define CLEAN16 \
    CSWAP(0, 8)  CSWAP(1, 9)  CSWAP(2, 10) CSWAP(3, 11) \
    CSWAP(4, 12) CSWAP(5, 13) CSWAP(6, 14) CSWAP(7, 15) \
    CSWAP(0, 4)  CSWAP(1, 5)  CSWAP(2, 6)  CSWAP(3, 7)  \
    CSWAP(8, 12) CSWAP(9, 13) CSWAP(10, 14) CSWAP(11, 15)\
    CSWAP(0, 2)  CSWAP(1, 3)  CSWAP(4, 6)  CSWAP(5, 7)  \
    CSWAP(8, 10) CSWAP(9, 11) CSWAP(12, 14) CSWAP(13, 15)\
    CSWAP(0, 1)  CSWAP(2, 3)  CSWAP(4, 5)  CSWAP(6, 7)  \
    CSWAP(8, 9)  CSWAP(10, 11) CSWAP(12, 13) CSWAP(14, 15)

__global__ __launch_bounds__(1024, 4) void knn_spatial_kernel(
    const float4* __restrict__ vps,
    const int*    __restrict__ vidx,
    const int*    __restrict__ prefix,
    const float*  __restrict__ grid_verts,
    const float*  __restrict__ tau,
    int* __restrict__ knn_idx)
{
    __shared__ unsigned long long buf[8192];   // 64 KB: scan FIFO, then merge slots
    const int tid  = threadIdx.x;
    const int lane = tid & 63;
    const int w    = tid >> 6;                 // wave id

    // brick decomposition: 8x8x8 bricks of 4x4x4 grid cells; lane -> local cell
    const int bx4 = (blockIdx.x >> 6) * 4;
    const int by4 = ((blockIdx.x >> 3) & 7) * 4;
    const int bz4 = (blockIdx.x & 7) * 4;
    const int lx = lane >> 4, ly = (lane >> 2) & 3, lz = lane & 3;
    const int m = ((bx4 + lx) * 32 + (by4 + ly)) * 32 + (bz4 + lz);

    const float q0 = __fmul_rn(grid_verts[m * 3 + 0], 32.0f);
    const float q1 = __fmul_rn(grid_verts[m * 3 + 1], 32.0f);
    const float q2 = __fmul_rn(grid_verts[m * 3 + 2], 32.0f);
    const float qq = __fadd_rn(__fadd_rn(__fmul_rn(q0, q0), __fmul_rn(q1, q1)),
                               __fmul_rn(q2, q2));

    const float tm = tau[m];
    // seed = key(bound), idx 0; bound > all golden top-16 d2 (validated margin)
    const float bound = tm + 0.13f;
    unsigned int bb = __float_as_uint(bound) ^ 0x80000000u;  // bound > 0
    const unsigned long long seed = ((unsigned long long)bb << 32);

    unsigned long long a[KNN];
#pragma unroll
    for (int s = 0; s < KNN; ++s) a[s] = seed;
    float gd = bound;      // d2-domain gate = d2 part of a[15]
    int cnt = 0;

    // block-uniform tau max (identical in every wave: lane->query map is
    // wave-independent)
    float tmax = tm;
#pragma unroll
    for (int off = 32; off; off >>= 1)
        tmax = fmaxf(tmax, __uint_as_float(__shfl_xor(__float_as_uint(tmax), off)));

    int rs = (int)sqrtf(tmax) + 1;
    rs = min(31, max(1, rs));                  // poison-bounded
    const int xlo = max(0, bx4 - rs), xhi = min(31, bx4 + 3 + rs);
    const int ylo = max(0, by4 - rs), yhi = min(31, by4 + 3 + rs);
    const int ny = yhi - ylo + 1;
    const int npair = (xhi - xlo + 1) * ny;

    int xx = xlo + w / ny;                     // w < 16, ny >= 8 on clean data
    int yy = ylo + w % ny;
    for (int pi = w; pi < npair; pi += 16) {
        // per-column distance budget (sphere clip); all-int fp32 => exact
        int cdx = max(0, max(bx4 - xx, xx - bx4 - 3));
        int cdy = max(0, max(by4 - yy, yy - by4 - 3));
        int mdx = max(0, cdx - 1), mdy = max(0, cdy - 1);
        float rem = tmax - (float)(mdx * mdx + mdy * mdy);
        if (rem >= 0.0f) {
            int zrc = (int)sqrtf(rem) + 1;
            zrc = min(31, max(0, zrc));        // poison-bounded
            const int zl = max(0, bz4 - zrc), zh = min(31, bz4 + 3 + zrc);
            const int cxx = min(xx, 31);       // poison-bounded
            const int c = (cxx * 32 + yy) * 32;
            int pstart = prefix[c + zl];
            int pend   = prefix[c + zh + 1];
            pstart = min(max(pstart, 0), NV);  // poison-bounded
            pend   = min(max(pend, pstart), NV);
#pragma unroll 2
            for (int p = pstart; p < pend; ++p) {
                float4 v = vps[p];
                float dot = fmaf(q2, v.z, fmaf(q1, v.y, __fmul_rn(q0, v.x)));
                // == (qq+rr) - 2*dot bit-exactly (2*dot exact)
                float d2 = fmaf(-2.0f, dot, __fadd_rn(qq, v.w));
                if (d2 <= gd) {     // conservative: ties resolved by insert
                    unsigned long long key = d2key(d2, (unsigned int)vidx[p]);
                    if (cnt < CAPB) { buf[cnt * 1024 + tid] = key; ++cnt; }
                    else {  // burst overflow: exact direct insert, tighten gate
                        key_insert(a, key);
                        gd = key_d2f(a[KNN - 1]);
                    }
                }
            }
            // deferred fixed-cost drain: only when some lane is near-full
            if (__any(cnt >= 5)) {
                unsigned long long f[CAPB];
#pragma unroll
                for (int k = 0; k < CAPB; ++k)
                    f[k] = (k < cnt) ? buf[k * 1024 + tid] : ~0ULL;
                // Batcher odd-even mergesort, 8 elements, 19 comparators
                FSWAP(0,1) FSWAP(2,3) FSWAP(4,5) FSWAP(6,7)
                FSWAP(0,2) FSWAP(1,3) FSWAP(4,6) FSWAP(5,7)
                FSWAP(1,2) FSWAP(5,6)
                FSWAP(0,4) FSWAP(1,5) FSWAP(2,6) FSWAP(3,7)
                FSWAP(2,4) FSWAP(3,5)
                FSWAP(1,2) FSWAP(3,4) FSWAP(5,6)
                // bitonic 16+8 min-merge (upper 8 of b = +INF) + clean
#pragma unroll
                for (int j = 0; j < 8; ++j) {
                    unsigned long long b = f[7 - j];
                    if (b < a[8 + j]) a[8 + j] = b;
                }
                CLEAN16
                gd = key_d2f(a[KNN - 1]);
                cnt = 0;
            }
        }
        // advance (xx,yy) by 16 columns; ny >= 8 => at most 2 carries
        yy += 16;
        if (yy > yhi) { yy -= ny; ++xx; }
        if (yy > yhi) { yy -= ny; ++xx; }
    }

    // final drain (FIFO may hold keys)
    if (__any(cnt > 0)) {
        unsigned long long f[CAPB];
#pragma unroll
        for (int k = 0; k < CAPB; ++k)
            f[k] = (k < cnt) ? buf[k * 1024 + tid] : ~0ULL;
        FSWAP(0,1) FSWAP(2,3) FSWAP(4,5) FSWAP(6,7)
        FSWAP(0,2) FSWAP(1,3) FSWAP(4,6) FSWAP(5,7)
        FSWAP(1,2) FSWAP(5,6)
        FSWAP(0,4) FSWAP(1,5) FSWAP(2,6) FSWAP(3,7)
        FSWAP(2,4) FSWAP(3,5)
        FSWAP(1,2) FSWAP(3,4) FSWAP(5,6)
#pragma unroll
        for (int j = 0; j < 8; ++j) {
            unsigned long long b = f[7 - j];
            if (b < a[8 + j]) a[8 + j] = b;
        }
        CLEAN16
    }

    // ---- cross-wave merge tree: 16 sorted lists -> 1, bitonic in registers ----
    // round half: waves [half,2*half) publish, waves [0,half) merge slot w.
    for (int half = 8; half >= 1; half >>= 1) {
        __syncthreads();                       // prior reads done before overwrite
        if (w >= half && w < 2 * half) {
            unsigned long long* dst = &buf[(w - half) * 1024];
#pragma unroll
            for (int s = 0; s < KNN; ++s) dst[s * 64 + lane] = a[s];
        }
        __syncthreads();
        if (w < half) {
            const unsigned long long* src = &buf[w * 1024];
            // L[i] = min(a[i], b[15-i]) : 16 smallest of union, bitonic
#pragma unroll
            for (int i = 0; i < KNN; ++i) {
                unsigned long long b = src[(KNN - 1 - i) * 64 + lane];
                a[i] = (b < a[i]) ? b : a[i];
            }
            CLEAN16
        }
    }

    if (w == 0) {
#pragma unroll
        for (int s = 0; s < KNN; ++s)
            knn_idx[m * KNN + s] = (int)(a[s] & 0xFFFFFFFFu);
    }
}

// ===========================================================================
// Main MLP (unchanged from R7/R8 — passed; LN stats deduplicated via readlane)
// ===========================================================================
__device__ __forceinline__ float gelu_fast(float x) {
    float t = fmaf(0.044715f, x * x, 1.0f);
    float u = 0.7978845608028654f * x * t;
    float e = __expf(-2.0f * u);
    return x * __builtin_amdgcn_rcpf(1.0f + e);
}

__device__ __forceinline__ float lane_bcast(float v, int lane) {
    return __uint_as_float(__builtin_amdgcn_readlane(__float_as_uint(v), lane));
}

__global__ __launch_bounds__(MLP_BLOCK) void mlp_kernel(
    const float* __restrict__ verts,
    const float* __restrict__ grid_verts,
    const float* __restrict__ grid_feat,
    const float* __restrict__ pre,
    const float* __restrict__ aux,
    const float* __restrict__ cst,
    const int*   __restrict__ knn_idx,
    const float* __restrict__ ew1,
    const float* __restrict__ eg1, const float* __restrict__ ebt1,
    const float* __restrict__ ew2, const float* __restrict__ eb2,
    const float* __restrict__ ow1, const float* __restrict__ ob1,
    const float* __restrict__ og1, const float* __restrict__ obt1,
    const float* __restrict__ ow2, const float* __restrict__ ob2,
    float* __restrict__ out)
{
    __shared__ float s_ew1r[3 * 64];
    __shared__ float s_ew2[64 * 64];
    __shared__ float s_ow1[160 * 64];
    __shared__ float s_ow2[64 * 64];
    __shared__ float s_eg1[64], s_ebt1[64], s_eb2[64];
    __shared__ float s_ob1[64], s_og1[64], s_obt1[64], s_ob2[64];

    const int tid = threadIdx.x;
    for (int t = tid; t < 3 * 64;  t += MLP_BLOCK) s_ew1r[t] = ew1[32 * 64 + t];
    for (int t = tid; t < 64 * 64; t += MLP_BLOCK) s_ew2[t]  = ew2[t];
    for (int t = tid; t < 160 * 64; t += MLP_BLOCK) s_ow1[t] = ow1[t];
    for (int t = tid; t < 64 * 64; t += MLP_BLOCK) s_ow2[t]  = ow2[t];
    if (tid < 64) {
        s_eg1[tid] = eg1[tid];  s_ebt1[tid] = ebt1[tid]; s_eb2[tid] = eb2[tid];
        s_ob1[tid] = ob1[tid];  s_og1[tid] = og1[tid];
        s_obt1[tid] = obt1[tid]; s_ob2[tid] = ob2[tid];
    }
    __syncthreads();

    const int lane = tid & 63;
    const int wave = tid >> 6;
    const int c    = lane;
    const int grp  = blockIdx.x * WPB + wave;
    const int m0   = __builtin_amdgcn_readfirstlane(grp * MT);

    const float Ws0 = cst[0], Ws1 = cst[1], Ws2 = cst[2];
    const float Gxx = cst[3], Gyy = cst[4], Gzz = cst[5];
    const float Gxy = cst[6], Gxz = cst[7], Gyz = cst[8];

    const float inv64 = 1.0f / 64.0f;

    // ---- LN-stat setup: lane l owns combo (pp = l>>4, jq = l&15) ----
    const int pp = lane >> 4, jq = lane & 15;
    const int nl = knn_idx[(m0 + pp) * KNN + jq];
    float S1  = aux[nl * 8 + 0], Q = aux[nl * 8 + 1];
    float P1x = aux[nl * 8 + 2], P1y = aux[nl * 8 + 3], P1z = aux[nl * 8 + 4];
    float rxl = verts[nl * 3 + 0] - grid_verts[(m0 + pp) * 3 + 0];
    float ryl = verts[nl * 3 + 1] - grid_verts[(m0 + pp) * 3 + 1];
    float rzl = verts[nl * 3 + 2] - grid_verts[(m0 + pp) * 3 + 2];
    float s1l = S1 + rxl * Ws0 + ryl * Ws1 + rzl * Ws2;
    float s2l = Q + 2.0f * (rxl * P1x + ryl * P1y + rzl * P1z)
              + rxl * rxl * Gxx + ryl * ryl * Gyy + rzl * rzl * Gzz
              + 2.0f * (rxl * ryl * Gxy + rxl * rzl * Gxz + ryl * rzl * Gyz);
    float meanl  = s1l * inv64;
    float varl   = s2l * inv64 - meanl * meanl;
    float irstdl = rsqrtf(varl + 1e-5f);

    float gsum[MT];
#pragma unroll
    for (int p = 0; p < MT; ++p) gsum[p] = 0.0f;

#pragma unroll
    for (int p = 0; p < MT; ++p) {
#pragma unroll
        for (int j = 0; j < KNN; ++j) {
            const int src = p * 16 + j;   // compile-time readlane index
            int n = __builtin_amdgcn_readfirstlane(knn_idx[(m0 + p) * KNN + j]);
            float hv = pre[(size_t)n * COUT + c];
            float rx = lane_bcast(rxl, src);
            float ry = lane_bcast(ryl, src);
            float rz = lane_bcast(rzl, src);
            hv = fmaf(rx, s_ew1r[0 * 64 + c], hv);
            hv = fmaf(ry, s_ew1r[1 * 64 + c], hv);
            hv = fmaf(rz, s_ew1r[2 * 64 + c], hv);
            float mean  = lane_bcast(meanl, src);
            float irstd = lane_bcast(irstdl, src);
            float xn = (hv - mean) * irstd;
            gsum[p] += gelu_fast(xn * s_eg1[c] + s_ebt1[c]);
        }
    }

    float A[MT];
#pragma unroll
    for (int p = 0; p < MT; ++p) { gsum[p] *= (1.0f / 16.0f); A[p] = s_eb2[c]; }
    for (int jj = 0; jj < 64; ++jj) {
        float w = s_ew2[jj * 64 + c];
#pragma unroll
        for (int p = 0; p < MT; ++p)
            A[p] = fmaf(lane_bcast(gsum[p], jj), w, A[p]);
    }

    float gfa[MT], gfb[MT];
#pragma unroll
    for (int p = 0; p < MT; ++p) {
        gfa[p] = grid_feat[(size_t)(m0 + p) * CPROV + c];
        gfb[p] = grid_feat[(size_t)(m0 + p) * CPROV + 64 + (c & 31)];
    }
    float t1[MT];
#pragma unroll
    for (int p = 0; p < MT; ++p) t1[p] = s_ob1[c];
    for (int jj = 0; jj < 64; ++jj) {
        float w = s_ow1[jj * 64 + c];
#pragma unroll
        for (int p = 0; p < MT; ++p)
            t1[p] = fmaf(lane_bcast(A[p], jj), w, t1[p]);
    }
    for (int i = 0; i < 64; ++i) {
        float w = s_ow1[(64 + i) * 64 + c];
#pragma unroll
        for (int p = 0; p < MT; ++p)
            t1[p] = fmaf(lane_bcast(gfa[p], i), w, t1[p]);
    }
    for (int i = 0; i < 32; ++i) {
        float w = s_ow1[(128 + i) * 64 + c];
#pragma unroll
        for (int p = 0; p < MT; ++p)
            t1[p] = fmaf(lane_bcast(gfb[p], i), w, t1[p]);
    }

#pragma unroll
    for (int p = 0; p < MT; ++p) {
        float x = t1[p];
        float s = x, s2 = x * x;
#pragma unroll
        for (int off = 32; off; off >>= 1) {
            s  += __shfl_xor(s, off);
            s2 += __shfl_xor(s2, off);
        }
        float mean = s * inv64;
        float var  = s2 * inv64 - mean * mean;
        float xn = (x - mean) * rsqrtf(var + 1e-5f);
        t1[p] = gelu_fast(xn * s_og1[c] + s_obt1[c]);
    }

    float o[MT];
#pragma unroll
    for (int p = 0; p < MT; ++p) o[p] = s_ob2[c];
    for (int jj = 0; jj < 64; ++jj) {
        float w = s_ow2[jj * 64 + c];
#pragma unroll
        for (int p = 0; p < MT; ++p)
            o[p] = fmaf(lane_bcast(t1[p], jj), w, o[p]);
    }
#pragma unroll
    for (int p = 0; p < MT; ++p)
        out[(size_t)(m0 + p) * COUT + c] = o[p];
}

// ---------------------------------------------------------------------------
extern "C" void kernel_launch(void* const* d_in, const int* in_sizes, int n_in,
                              void* d_out, int out_size, void* d_ws, size_t ws_size,
                              hipStream_t stream)
{
    const float* verts  = (const float*)d_in[0];
    const float* feats  = (const float*)d_in[1];
    const float* gverts = (const float*)d_in[2];
    const float* gfeat  = (const float*)d_in[3];
    const float* ew1    = (const float*)d_in[4];
    const float* eb1    = (const float*)d_in[5];
    const float* eg1    = (const float*)d_in[6];
    const float* ebt1   = (const float*)d_in[7];
    const float* ew2    = (const float*)d_in[8];
    const float* eb2    = (const float*)d_in[9];
    const float* ow1    = (const float*)d_in[10];
    const float* ob1    = (const float*)d_in[11];
    const float* og1    = (const float*)d_in[12];
    const float* obt1   = (const float*)d_in[13];
    const float* ow2    = (const float*)d_in[14];
    const float* ob2    = (const float*)d_in[15];
    float* out = (float*)d_out;

    char* ws = (char*)d_ws;
    int*    counts  = (int*)(ws + 0);              // 128 KB
    int*    cursor  = (int*)(ws + 131072);         // 128 KB (memset with counts)
    int*    prefix  = (int*)(ws + 262144);         // 32769 ints -> ends 393220
    float*  tau     = (float*)(ws + 393224);       // 128 KB -> ends 524296
    int*    knn_idx = (int*)(ws + 524296);         // 2 MB -> ends 2621448
    float4* vps     = (float4*)(ws + 2621456);     // 128 KB (16-aligned) -> 2752528
    int*    vidx    = (int*)(ws + 2752528);        // 32 KB -> ends 2785296
    float*  pre     = (float*)(ws + 2785296);      // 2 MB -> ends 4882448
    float*  aux     = (float*)(ws + 4882448);      // 256 KB -> ends 5144592
    float*  cst     = (float*)(ws + 5144592);      // 64 B

    hipMemsetAsync(counts, 0, 262144, stream);     // counts + cursor
    fused_pre_kernel<<<2081, 256, 0, stream>>>(verts, feats, ew1, eb1,
                                               counts, pre, aux, cst);
    prefix_kernel<<<1, 1024, 0, stream>>>(counts, prefix);
    fused_grid_kernel<<<8224, 256, 0, stream>>>(verts, gverts, prefix, cursor,
                                                tau, vps, vidx);
    knn_spatial_kernel<<<NM / 64, 1024, 0, stream>>>(vps, vidx, prefix, gverts, tau, knn_idx);
    mlp_kernel<<<NM / (MT * WPB), MLP_BLOCK, 0, stream>>>(verts, gverts, gfeat,
        pre, aux, cst, knn_idx,
        ew1, eg1, ebt1, ew2, eb2, ow1, ob1, og1, obt1, ow2, ob2, out);
}